// Round 5
// baseline (362.588 us; speedup 1.0000x reference)
//
#include <hip/hip_runtime.h>
#include <hip/hip_bf16.h>

#define HW 4096
#define NC 512
#define NB 4

typedef float f32x4 __attribute__((ext_vector_type(4)));
typedef short bf16x8 __attribute__((ext_vector_type(8)));
typedef unsigned short ushort_t;

#define GLOAD_LDS(g, s) __builtin_amdgcn_global_load_lds((const __attribute__((address_space(1))) void*)(g), (__attribute__((address_space(3))) void*)(s), 16, 0, 0)

__device__ __forceinline__ unsigned short f2bf(float f){
  unsigned int u = __builtin_bit_cast(unsigned int, f);
  u += 0x7FFFu + ((u >> 16) & 1u);
  return (unsigned short)(u >> 16);
}
__device__ __forceinline__ float bf2f(unsigned short h){
  unsigned int u = ((unsigned int)h) << 16;
  return __builtin_bit_cast(float, u);
}

// ---------------- W -> bf16 hi (+lo for q/k rows 0..127) ----------------
__global__ __launch_bounds__(256) void wsplit_kernel(
    const float* __restrict__ Wq, const float* __restrict__ Wk,
    const float* __restrict__ Wv, ushort_t* __restrict__ wh, ushort_t* __restrict__ wl)
{
  long e = ((long)blockIdx.x * 256 + threadIdx.x) * 8;
  int r = (int)(e >> 9), c = (int)(e & 511);
  const float* src = (r < 64)  ? Wq + (long)r * 512 + c
                   : (r < 128) ? Wk + (long)(r - 64) * 512 + c
                               : Wv + (long)(r - 128) * 512 + c;
  f32x4 v0 = *reinterpret_cast<const f32x4*>(src);
  f32x4 v1 = *reinterpret_cast<const f32x4*>(src + 4);
  ushort_t h[8], l[8];
  #pragma unroll
  for (int j = 0; j < 4; j++){ h[j] = f2bf(v0[j]); l[j] = f2bf(v0[j] - bf2f(h[j])); }
  #pragma unroll
  for (int j = 0; j < 4; j++){ h[4+j] = f2bf(v1[j]); l[4+j] = f2bf(v1[j] - bf2f(h[4+j])); }
  *reinterpret_cast<bf16x8*>(wh + e) = *reinterpret_cast<bf16x8*>(h);
  if (r < 128) *reinterpret_cast<bf16x8*>(wl + e) = *reinterpret_cast<bf16x8*>(l);
}

// ---------------- x [b][c][px] fp32 -> xt hi/lo [b][px][c] bf16 ----------------
__global__ __launch_bounds__(256) void split_kernel(
    const float* __restrict__ x, ushort_t* __restrict__ xth, ushort_t* __restrict__ xtl)
{
  const int i0 = blockIdx.x * 64;
  const int c0 = blockIdx.y * 64;
  const int b  = blockIdx.z;
  const int tid = threadIdx.x;
  const int tx = tid & 63, ty = tid >> 6;
  __shared__ float ts[64][65];
  #pragma unroll
  for (int u = 0; u < 16; u++){
    int cl = ty * 16 + u;
    ts[cl][tx] = x[((long)b * NC + c0 + cl) * HW + i0 + tx];
  }
  __syncthreads();
  const int px = tid >> 2;
  const int cs = (tid & 3) * 16;
  ushort_t h[16], l[16];
  #pragma unroll
  for (int e = 0; e < 16; e++){
    float v = ts[cs + e][px];
    h[e] = f2bf(v);
    l[e] = f2bf(v - bf2f(h[e]));
  }
  long base = ((long)b * HW + i0 + px) * 512 + c0 + cs;
  *reinterpret_cast<bf16x8*>(xth + base)     = *reinterpret_cast<bf16x8*>(h);
  *reinterpret_cast<bf16x8*>(xth + base + 8) = *reinterpret_cast<bf16x8*>(h + 8);
  *reinterpret_cast<bf16x8*>(xtl + base)     = *reinterpret_cast<bf16x8*>(l);
  *reinterpret_cast<bf16x8*>(xtl + base + 8) = *reinterpret_cast<bf16x8*>(l + 8);
}

// ---------------- MFMA projection GEMM (unchanged from round 3) ----------------
__global__ __launch_bounds__(256) void gemm_kernel(
    const ushort_t* __restrict__ xth, const ushort_t* __restrict__ xtl,
    const ushort_t* __restrict__ wh, const ushort_t* __restrict__ wl,
    const float* __restrict__ bq, const float* __restrict__ bk, const float* __restrict__ bv,
    ushort_t* __restrict__ qhi, ushort_t* __restrict__ qlo,
    ushort_t* __restrict__ khi, ushort_t* __restrict__ klo,
    ushort_t* __restrict__ vv)
{
  extern __shared__ char lds[];
  const int it = blockIdx.x;
  const int rg = blockIdx.y;
  const int b  = blockIdx.z;
  const int i0 = it * 128;
  const int tid = threadIdx.x;
  const int w = tid >> 6;
  const int lane = tid & 63;
  const int g = lane >> 4, n = lane & 15;
  const int wy = w >> 1, wx = w & 1;

  f32x4 acc[4][4];
  #pragma unroll
  for (int a = 0; a < 4; a++)
    #pragma unroll
    for (int m = 0; m < 4; m++) acc[a][m] = (f32x4){0.f, 0.f, 0.f, 0.f};

  const long xrow = (long)b * HW + i0;

  auto stage = [&](int bsel, int c0s){
    char* dbase = lds + bsel * 32768 + (w << 10);
    #pragma unroll
    for (int u = 0; u < 4; u++){
      int idx = (u << 8) | tid;
      int px = idx >> 3;
      int chs = (idx & 7) ^ (px & 7);
      long go = (xrow + px) * 512 + c0s + chs * 8;
      GLOAD_LDS(xth + go, dbase + (u << 12));
      GLOAD_LDS(xtl + go, dbase + 16384 + (u << 12));
    }
  };

  stage(0, 0);
  asm volatile("s_waitcnt vmcnt(0)" ::: "memory");
  __syncthreads();

  int cur = 0;
  for (int t = 0; t < 8; t++){
    const int c0 = t << 6;
    bf16x8 wfh[4][2], wfl[4][2];
    #pragma unroll
    for (int a = 0; a < 4; a++){
      long R = (long)(rg * 128 + wx * 64 + a * 16 + n) * 512 + c0 + g * 8;
      wfh[a][0] = *reinterpret_cast<const bf16x8*>(wh + R);
      wfh[a][1] = *reinterpret_cast<const bf16x8*>(wh + R + 32);
    }
    if (rg == 0){
      #pragma unroll
      for (int a = 0; a < 4; a++){
        long R = (long)(wx * 64 + a * 16 + n) * 512 + c0 + g * 8;
        wfl[a][0] = *reinterpret_cast<const bf16x8*>(wl + R);
        wfl[a][1] = *reinterpret_cast<const bf16x8*>(wl + R + 32);
      }
    }
    if (t < 7) stage(cur ^ 1, (t + 1) << 6);
    bf16x8 xh[4][2], xl[4][2];
    const char* buf = lds + cur * 32768;
    #pragma unroll
    for (int m = 0; m < 4; m++){
      int px = wy * 64 + m * 16 + n;
      const char* row = buf + px * 128;
      #pragma unroll
      for (int ks = 0; ks < 2; ks++){
        int off = (((ks << 2) | g) ^ (px & 7)) << 4;
        xh[m][ks] = *reinterpret_cast<const bf16x8*>(row + off);
        xl[m][ks] = *reinterpret_cast<const bf16x8*>(row + 16384 + off);
      }
    }
    __builtin_amdgcn_s_setprio(1);
    if (rg == 0){
      #pragma unroll
      for (int a = 0; a < 4; a++)
        #pragma unroll
        for (int m = 0; m < 4; m++)
          #pragma unroll
          for (int ks = 0; ks < 2; ks++){
            acc[a][m] = __builtin_amdgcn_mfma_f32_16x16x32_bf16(xh[m][ks], wfh[a][ks], acc[a][m], 0, 0, 0);
            acc[a][m] = __builtin_amdgcn_mfma_f32_16x16x32_bf16(xl[m][ks], wfh[a][ks], acc[a][m], 0, 0, 0);
            acc[a][m] = __builtin_amdgcn_mfma_f32_16x16x32_bf16(xh[m][ks], wfl[a][ks], acc[a][m], 0, 0, 0);
          }
    } else {
      #pragma unroll
      for (int a = 0; a < 4; a++)
        #pragma unroll
        for (int m = 0; m < 4; m++)
          #pragma unroll
          for (int ks = 0; ks < 2; ks++){
            acc[a][m] = __builtin_amdgcn_mfma_f32_16x16x32_bf16(wfh[a][ks], xh[m][ks], acc[a][m], 0, 0, 0);
            acc[a][m] = __builtin_amdgcn_mfma_f32_16x16x32_bf16(wfh[a][ks], xl[m][ks], acc[a][m], 0, 0, 0);
          }
    }
    __builtin_amdgcn_s_setprio(0);
    asm volatile("s_waitcnt vmcnt(0)" ::: "memory");
    __syncthreads();
    cur ^= 1;
  }

  if (rg == 0){
    ushort_t* hs = wx ? khi : qhi;
    ushort_t* ls = wx ? klo : qlo;
    const float* bias = wx ? bk : bq;
    #pragma unroll
    for (int a = 0; a < 4; a++){
      float bb = bias[a * 16 + n];
      #pragma unroll
      for (int m = 0; m < 4; m++){
        #pragma unroll
        for (int r4 = 0; r4 < 4; r4++){
          int px = wy * 64 + m * 16 + g * 4 + r4;
          float v = acc[a][m][r4] + bb;
          ushort_t h = f2bf(v);
          ushort_t l = f2bf(v - bf2f(h));
          long ad = (xrow + px) * 64 + a * 16 + n;
          hs[ad] = h;
          ls[ad] = l;
        }
      }
    }
  } else {
    #pragma unroll
    for (int a = 0; a < 4; a++){
      #pragma unroll
      for (int r4 = 0; r4 < 4; r4++){
        int C = (rg - 1) * 128 + wx * 64 + a * 16 + g * 4 + r4;
        float bb = bv[C];
        #pragma unroll
        for (int m = 0; m < 4; m++){
          int px = wy * 64 + m * 16 + n;
          vv[((long)b * NC + C) * HW + i0 + px] = f2bf(acc[a][m][r4] + bb);
        }
      }
    }
  }
}

// ---------------- flash attention: 128 q rows/block, j-split x2, 64-j iters ----------------
// grid (32 qtiles, 2 j-halves, NB), block 512 (8 waves).
// wave w: rg = w>>1 -> q rows [qt*128 + rg*32, +32) (2 m-subtiles of 16), ch = w&1 -> 256-ch half.
// 32 iterations over 64-j subtiles of this block's 2048-j half.
// LDS (round-3-identical micro-layouts):
//   [0,32K)  K double buffer (16KB each: hi 8K + lo 8K, [64j][64d] rows 128B, XOR-8)
//   [32K,96K) V single buffer ([512c][64j] rows 128B, XOR-8)
//   [96K,130K) per-wave P scratch fp32 [16][68], reused for m=0 then m=1
__global__ __launch_bounds__(512, 1) void attn_kernel(
    const ushort_t* __restrict__ qhi, const ushort_t* __restrict__ qlo,
    const ushort_t* __restrict__ khi, const ushort_t* __restrict__ klo,
    const ushort_t* __restrict__ vv,
    ushort_t* __restrict__ p0, ushort_t* __restrict__ p1,
    float* __restrict__ mbuf, float* __restrict__ lbuf)
{
  extern __shared__ char smem[];
  const int qt = blockIdx.x;
  const int jh = blockIdx.y;
  const int b  = blockIdx.z;
  const int tid = threadIdx.x;
  const int w = tid >> 6;
  const int lane = tid & 63;
  const int g = lane >> 4, n = lane & 15;
  const int rg = w >> 1, ch = w & 1;
  const int i0w = qt * 128 + rg * 32;
  const int c0w = ch * 256;
  const int jbase = jh * 2048;

  float* psw = (float*)(smem + 98304) + w * (16 * 68);

  // K staging: kj = tid>>3 (64 j rows), dblock pre-swizzled; each thread loads hi+lo chunk
  const int kj = tid >> 3;
  const int kdblk = (tid & 7) ^ (kj & 7);
  const long kgbase = ((long)b * HW + kj) * 64 + kdblk * 8;

  auto stageK = [&](int bsel, int j0){
    char* dst = smem + bsel * 16384 + (w << 10);
    GLOAD_LDS(khi + kgbase + (long)j0 * 64, dst);
    GLOAD_LDS(klo + kgbase + (long)j0 * 64, dst + 8192);
  };
  auto stageV = [&](int j0){
    #pragma unroll
    for (int r = 0; r < 8; r++){
      int ss = (r << 9) | tid;
      int c = ss >> 3;
      int jblk = (ss & 7) ^ (c & 7);
      long goff = (long)b * (NC * HW) + (long)c * HW + j0 + jblk * 8;
      GLOAD_LDS(vv + goff, smem + 32768 + (r << 13) + (w << 10));
    }
  };

  // Q fragments: 2 m-subtiles x hi/lo x 2 k-slices
  bf16x8 aqh[2][2], aql[2][2];
  #pragma unroll
  for (int m = 0; m < 2; m++){
    long qb = ((long)b * HW + i0w + m * 16 + n) * 64 + g * 8;
    aqh[m][0] = *reinterpret_cast<const bf16x8*>(qhi + qb);
    aqh[m][1] = *reinterpret_cast<const bf16x8*>(qhi + qb + 32);
    aql[m][0] = *reinterpret_cast<const bf16x8*>(qlo + qb);
    aql[m][1] = *reinterpret_cast<const bf16x8*>(qlo + qb + 32);
  }

  f32x4 acc[2][16];
  #pragma unroll
  for (int m = 0; m < 2; m++)
    #pragma unroll
    for (int t = 0; t < 16; t++) acc[m][t] = (f32x4){0.f, 0.f, 0.f, 0.f};
  float mrow[2][4], lrow[2][4];
  #pragma unroll
  for (int m = 0; m < 2; m++)
    #pragma unroll
    for (int r = 0; r < 4; r++){ mrow[m][r] = -1e30f; lrow[m][r] = 0.f; }

  stageK(0, jbase);
  stageV(jbase);
  asm volatile("s_waitcnt vmcnt(0)" ::: "memory");
  __syncthreads();

  int cur = 0;
  for (int t = 0; t < 32; t++){
    // 1. prefetch K[t+1] into the other buffer (stays in flight across QK+softmax)
    stageK(cur ^ 1, jbase + ((t + 1) & 31) * 64);
    // 2. QK (3-term hi/lo), 64 j per iter: sv[m][nt]
    f32x4 sv[2][4];
    {
      const char* kb0 = smem + cur * 16384;
      __builtin_amdgcn_s_setprio(1);
      #pragma unroll
      for (int nt = 0; nt < 4; nt++){
        int jl = nt * 16 + n;
        const char* kb = kb0 + jl * 128;
        int x0 = (g ^ (jl & 7)) << 4;
        int x1 = ((g + 4) ^ (jl & 7)) << 4;
        bf16x8 bh0 = *(const bf16x8*)(kb + x0);
        bf16x8 bh1 = *(const bf16x8*)(kb + x1);
        bf16x8 bl0 = *(const bf16x8*)(kb + 8192 + x0);
        bf16x8 bl1 = *(const bf16x8*)(kb + 8192 + x1);
        #pragma unroll
        for (int m = 0; m < 2; m++){
          f32x4 s = (f32x4){0.f, 0.f, 0.f, 0.f};
          s = __builtin_amdgcn_mfma_f32_16x16x32_bf16(aqh[m][0], bh0, s, 0, 0, 0);
          s = __builtin_amdgcn_mfma_f32_16x16x32_bf16(aqh[m][1], bh1, s, 0, 0, 0);
          s = __builtin_amdgcn_mfma_f32_16x16x32_bf16(aql[m][0], bh0, s, 0, 0, 0);
          s = __builtin_amdgcn_mfma_f32_16x16x32_bf16(aql[m][1], bh1, s, 0, 0, 0);
          s = __builtin_amdgcn_mfma_f32_16x16x32_bf16(aqh[m][0], bl0, s, 0, 0, 0);
          s = __builtin_amdgcn_mfma_f32_16x16x32_bf16(aqh[m][1], bl1, s, 0, 0, 0);
          sv[m][nt] = s;
        }
      }
      __builtin_amdgcn_s_setprio(0);
    }
    // 3. online softmax + P roundtrip, two m-phases sharing one P scratch
    bf16x8 pa[2][2];
    #pragma unroll
    for (int m = 0; m < 2; m++){
      float mnew[4]; int upd = 0;
      #pragma unroll
      for (int r = 0; r < 4; r++){
        float tmx = fmaxf(fmaxf(sv[m][0][r], sv[m][1][r]), fmaxf(sv[m][2][r], sv[m][3][r]));
        tmx = fmaxf(tmx, __shfl_xor(tmx, 1));
        tmx = fmaxf(tmx, __shfl_xor(tmx, 2));
        tmx = fmaxf(tmx, __shfl_xor(tmx, 4));
        tmx = fmaxf(tmx, __shfl_xor(tmx, 8));
        mnew[r] = fmaxf(mrow[m][r], tmx);
        upd |= (mnew[r] > mrow[m][r]) ? 1 : 0;
      }
      if (__any(upd)){
        #pragma unroll
        for (int r = 0; r < 4; r++){
          float sc = __expf(mrow[m][r] - mnew[r]);
          lrow[m][r] *= sc;
          mrow[m][r] = mnew[r];
          #pragma unroll
          for (int ct = 0; ct < 16; ct++) acc[m][ct][r] *= sc;
        }
      }
      float p[4][4];
      #pragma unroll
      for (int nt = 0; nt < 4; nt++)
        #pragma unroll
        for (int r = 0; r < 4; r++)
          p[nt][r] = __expf(sv[m][nt][r] - mrow[m][r]);
      #pragma unroll
      for (int r = 0; r < 4; r++){
        float rs = (p[0][r] + p[1][r]) + (p[2][r] + p[3][r]);
        rs += __shfl_xor(rs, 1);
        rs += __shfl_xor(rs, 2);
        rs += __shfl_xor(rs, 4);
        rs += __shfl_xor(rs, 8);
        lrow[m][r] += rs;
      }
      // P -> per-wave LDS (round-3 layout), read back as A-fragments
      #pragma unroll
      for (int nt = 0; nt < 4; nt++)
        #pragma unroll
        for (int r = 0; r < 4; r++)
          psw[(g * 4 + r) * 68 + nt * 16 + n] = p[nt][r];
      #pragma unroll
      for (int ks = 0; ks < 2; ks++){
        const f32x4* pr = reinterpret_cast<const f32x4*>(&psw[n * 68 + ks * 32 + g * 8]);
        f32x4 f0 = pr[0], f1 = pr[1];
        bf16x8 tt;
        tt[0] = (short)f2bf(f0[0]); tt[1] = (short)f2bf(f0[1]);
        tt[2] = (short)f2bf(f0[2]); tt[3] = (short)f2bf(f0[3]);
        tt[4] = (short)f2bf(f1[0]); tt[5] = (short)f2bf(f1[1]);
        tt[6] = (short)f2bf(f1[2]); tt[7] = (short)f2bf(f1[3]);
        pa[m][ks] = tt;
      }
    }
    // 4. wait V landed (K prefetch still in flight), sync all waves
    asm volatile("s_waitcnt vmcnt(2)" ::: "memory");
    __syncthreads();
    // 5. PV from V LDS tile
    {
      const char* vb0 = smem + 32768 + (c0w + n) * 128;
      __builtin_amdgcn_s_setprio(1);
      #pragma unroll
      for (int ct = 0; ct < 16; ct++){
        int cl = c0w + ct * 16 + n;
        const char* vb = vb0 + ct * 2048;
        int x0 = (g ^ (cl & 7)) << 4;
        int x1 = ((g + 4) ^ (cl & 7)) << 4;
        bf16x8 bv0 = *(const bf16x8*)(vb + x0);
        bf16x8 bv1 = *(const bf16x8*)(vb + x1);
        #pragma unroll
        for (int m = 0; m < 2; m++){
          acc[m][ct] = __builtin_amdgcn_mfma_f32_16x16x32_bf16(pa[m][0], bv0, acc[m][ct], 0, 0, 0);
          acc[m][ct] = __builtin_amdgcn_mfma_f32_16x16x32_bf16(pa[m][1], bv1, acc[m][ct], 0, 0, 0);
        }
      }
      __builtin_amdgcn_s_setprio(0);
    }
    // 6. drain K prefetch, sync (all waves done with V buffer), refill V
    asm volatile("s_waitcnt vmcnt(0)" ::: "memory");
    __syncthreads();
    if (t < 31) stageV(jbase + (t + 1) * 64);
    cur ^= 1;
  }

  // epilogue: unnormalized partial bf16 [b][i][c] + per-row (m,l)
  ushort_t* pd = jh ? p1 : p0;
  #pragma unroll
  for (int m = 0; m < 2; m++){
    #pragma unroll
    for (int ct = 0; ct < 16; ct++){
      #pragma unroll
      for (int r = 0; r < 4; r++){
        int i = i0w + m * 16 + g * 4 + r;
        int c = c0w + ct * 16 + n;
        pd[((long)b * HW + i) * NC + c] = f2bf(acc[m][ct][r]);
      }
    }
  }
  if (ch == 0 && n == 0){
    #pragma unroll
    for (int m = 0; m < 2; m++)
      #pragma unroll
      for (int r = 0; r < 4; r++){
        int gi = b * HW + i0w + m * 16 + g * 4 + r;
        mbuf[jh * (NB * HW) + gi] = mrow[m][r];
        lbuf[jh * (NB * HW) + gi] = lrow[m][r];
      }
  }
}

// ---------------- combine halves + epilogue: out = gamma * O + x ----------------
__global__ __launch_bounds__(256) void comb_kernel(
    const ushort_t* __restrict__ p0, const ushort_t* __restrict__ p1,
    const float* __restrict__ mbuf, const float* __restrict__ lbuf,
    const float* __restrict__ x, const float* __restrict__ gamma,
    float* __restrict__ out)
{
  const int it = blockIdx.x;
  const int ct = blockIdx.y;
  const int b  = blockIdx.z;
  const int i0 = it * 64, c0 = ct * 64;
  const int tid = threadIdx.x;
  const int tx = tid & 63, ty = tid >> 6;
  __shared__ float ts[64][65];
  __shared__ float f0s[64], f1s[64];
  const float gm = gamma[0];
  if (tid < 64){
    int gi = b * HW + i0 + tid;
    float m0 = mbuf[gi], m1 = mbuf[NB * HW + gi];
    float l0 = lbuf[gi], l1 = lbuf[NB * HW + gi];
    float M = fmaxf(m0, m1);
    float w0 = __expf(m0 - M), w1 = __expf(m1 - M);
    float rden = 1.f / (w0 * l0 + w1 * l1);
    f0s[tid] = w0 * rden;
    f1s[tid] = w1 * rden;
  }
  __syncthreads();
  #pragma unroll
  for (int u = 0; u < 16; u++){
    int il = ty * 16 + u;
    long pidx = ((long)b * HW + i0 + il) * NC + c0 + tx;
    ts[il][tx] = f0s[il] * bf2f(p0[pidx]) + f1s[il] * bf2f(p1[pidx]);
  }
  __syncthreads();
  #pragma unroll
  for (int u = 0; u < 16; u++){
    int cl = ty * 16 + u;
    long idx = ((long)b * NC + c0 + cl) * HW + i0 + tx;
    out[idx] = fmaf(gm, ts[tx][cl], x[idx]);
  }
}

extern "C" void kernel_launch(void* const* d_in, const int* in_sizes, int n_in,
                              void* d_out, int out_size, void* d_ws, size_t ws_size,
                              hipStream_t stream)
{
  const float* x  = (const float*)d_in[0];
  const float* Wq = (const float*)d_in[1];
  const float* bq = (const float*)d_in[2];
  const float* Wk = (const float*)d_in[3];
  const float* bk = (const float*)d_in[4];
  const float* Wv = (const float*)d_in[5];
  const float* bv = (const float*)d_in[6];
  const float* gamma = (const float*)d_in[7];
  float* out = (float*)d_out;

  char* ws = (char*)d_ws;
  const size_t MB = 1024 * 1024;
  ushort_t* xth = (ushort_t*)(ws);                 // 16 MB, reused as partial0
  ushort_t* xtl = (ushort_t*)(ws + 16 * MB);       // 16 MB, reused as partial1
  ushort_t* wh  = (ushort_t*)(ws + 32 * MB);       // 640 KB
  ushort_t* wl  = (ushort_t*)(ws + 32 * MB + 655360);  // 128 KB
  ushort_t* qhi = (ushort_t*)(ws + 33 * MB);       // 2 MB each
  ushort_t* qlo = (ushort_t*)(ws + 35 * MB);
  ushort_t* khi = (ushort_t*)(ws + 37 * MB);
  ushort_t* klo = (ushort_t*)(ws + 39 * MB);
  ushort_t* vv  = (ushort_t*)(ws + 41 * MB);       // 16 MB
  float*    mbuf = (float*)(ws + 57 * MB);         // 128 KB
  float*    lbuf = (float*)(ws + 57 * MB + 131072);// 128 KB
  ushort_t* part0 = xth;   // alias: xt dead after gemm
  ushort_t* part1 = xtl;

  wsplit_kernel<<<dim3(160), dim3(256), 0, stream>>>(Wq, Wk, Wv, wh, wl);
  split_kernel<<<dim3(64, 8, NB), dim3(256), 0, stream>>>(x, xth, xtl);

  const int GSMEM = 65536;
  hipFuncSetAttribute((const void*)gemm_kernel,
                      hipFuncAttributeMaxDynamicSharedMemorySize, GSMEM);
  gemm_kernel<<<dim3(32, 5, NB), dim3(256), GSMEM, stream>>>(
      xth, xtl, wh, wl, bq, bk, bv, qhi, qlo, khi, klo, vv);

  const int ASMEM = 133120;  // 32K K dbuf + 64K V + 34K P scratch
  hipFuncSetAttribute((const void*)attn_kernel,
                      hipFuncAttributeMaxDynamicSharedMemorySize, ASMEM);
  attn_kernel<<<dim3(32, 2, NB), dim3(512), ASMEM, stream>>>(
      qhi, qlo, khi, klo, vv, part0, part1, mbuf, lbuf);

  comb_kernel<<<dim3(64, 8, NB), dim3(256), 0, stream>>>(
      part0, part1, mbuf, lbuf, x, gamma, out);
}

// Round 6
// 356.707 us; speedup vs baseline: 1.0165x; 1.0165x over previous
//
#include <hip/hip_runtime.h>
#include <hip/hip_bf16.h>

#define HW 4096
#define NC 512
#define NB 4

typedef float f32x4 __attribute__((ext_vector_type(4)));
typedef short bf16x8 __attribute__((ext_vector_type(8)));
typedef unsigned short ushort_t;

#define GLOAD_LDS(g, s) __builtin_amdgcn_global_load_lds((const __attribute__((address_space(1))) void*)(g), (__attribute__((address_space(3))) void*)(s), 16, 0, 0)

__device__ __forceinline__ unsigned short f2bf(float f){
  unsigned int u = __builtin_bit_cast(unsigned int, f);
  u += 0x7FFFu + ((u >> 16) & 1u);
  return (unsigned short)(u >> 16);
}
__device__ __forceinline__ float bf2f(unsigned short h){
  unsigned int u = ((unsigned int)h) << 16;
  return __builtin_bit_cast(float, u);
}

// ---------------- W -> bf16 hi (+lo for q/k rows 0..127) ----------------
__global__ __launch_bounds__(256) void wsplit_kernel(
    const float* __restrict__ Wq, const float* __restrict__ Wk,
    const float* __restrict__ Wv, ushort_t* __restrict__ wh, ushort_t* __restrict__ wl)
{
  long e = ((long)blockIdx.x * 256 + threadIdx.x) * 8;
  int r = (int)(e >> 9), c = (int)(e & 511);
  const float* src = (r < 64)  ? Wq + (long)r * 512 + c
                   : (r < 128) ? Wk + (long)(r - 64) * 512 + c
                               : Wv + (long)(r - 128) * 512 + c;
  f32x4 v0 = *reinterpret_cast<const f32x4*>(src);
  f32x4 v1 = *reinterpret_cast<const f32x4*>(src + 4);
  ushort_t h[8], l[8];
  #pragma unroll
  for (int j = 0; j < 4; j++){ h[j] = f2bf(v0[j]); l[j] = f2bf(v0[j] - bf2f(h[j])); }
  #pragma unroll
  for (int j = 0; j < 4; j++){ h[4+j] = f2bf(v1[j]); l[4+j] = f2bf(v1[j] - bf2f(h[4+j])); }
  *reinterpret_cast<bf16x8*>(wh + e) = *reinterpret_cast<bf16x8*>(h);
  if (r < 128) *reinterpret_cast<bf16x8*>(wl + e) = *reinterpret_cast<bf16x8*>(l);
}

// ---------------- x [b][c][px] fp32 -> xt hi/lo [b][px][c] bf16 ----------------
__global__ __launch_bounds__(256) void split_kernel(
    const float* __restrict__ x, ushort_t* __restrict__ xth, ushort_t* __restrict__ xtl)
{
  const int i0 = blockIdx.x * 64;
  const int c0 = blockIdx.y * 64;
  const int b  = blockIdx.z;
  const int tid = threadIdx.x;
  const int tx = tid & 63, ty = tid >> 6;
  __shared__ float ts[64][65];
  #pragma unroll
  for (int u = 0; u < 16; u++){
    int cl = ty * 16 + u;
    ts[cl][tx] = x[((long)b * NC + c0 + cl) * HW + i0 + tx];
  }
  __syncthreads();
  const int px = tid >> 2;
  const int cs = (tid & 3) * 16;
  ushort_t h[16], l[16];
  #pragma unroll
  for (int e = 0; e < 16; e++){
    float v = ts[cs + e][px];
    h[e] = f2bf(v);
    l[e] = f2bf(v - bf2f(h[e]));
  }
  long base = ((long)b * HW + i0 + px) * 512 + c0 + cs;
  *reinterpret_cast<bf16x8*>(xth + base)     = *reinterpret_cast<bf16x8*>(h);
  *reinterpret_cast<bf16x8*>(xth + base + 8) = *reinterpret_cast<bf16x8*>(h + 8);
  *reinterpret_cast<bf16x8*>(xtl + base)     = *reinterpret_cast<bf16x8*>(l);
  *reinterpret_cast<bf16x8*>(xtl + base + 8) = *reinterpret_cast<bf16x8*>(l + 8);
}

// ---------------- MFMA projection GEMM (unchanged from round 3) ----------------
__global__ __launch_bounds__(256) void gemm_kernel(
    const ushort_t* __restrict__ xth, const ushort_t* __restrict__ xtl,
    const ushort_t* __restrict__ wh, const ushort_t* __restrict__ wl,
    const float* __restrict__ bq, const float* __restrict__ bk, const float* __restrict__ bv,
    ushort_t* __restrict__ qhi, ushort_t* __restrict__ qlo,
    ushort_t* __restrict__ khi, ushort_t* __restrict__ klo,
    ushort_t* __restrict__ vv)
{
  extern __shared__ char lds[];
  const int it = blockIdx.x;
  const int rg = blockIdx.y;
  const int b  = blockIdx.z;
  const int i0 = it * 128;
  const int tid = threadIdx.x;
  const int w = tid >> 6;
  const int lane = tid & 63;
  const int g = lane >> 4, n = lane & 15;
  const int wy = w >> 1, wx = w & 1;

  f32x4 acc[4][4];
  #pragma unroll
  for (int a = 0; a < 4; a++)
    #pragma unroll
    for (int m = 0; m < 4; m++) acc[a][m] = (f32x4){0.f, 0.f, 0.f, 0.f};

  const long xrow = (long)b * HW + i0;

  auto stage = [&](int bsel, int c0s){
    char* dbase = lds + bsel * 32768 + (w << 10);
    #pragma unroll
    for (int u = 0; u < 4; u++){
      int idx = (u << 8) | tid;
      int px = idx >> 3;
      int chs = (idx & 7) ^ (px & 7);
      long go = (xrow + px) * 512 + c0s + chs * 8;
      GLOAD_LDS(xth + go, dbase + (u << 12));
      GLOAD_LDS(xtl + go, dbase + 16384 + (u << 12));
    }
  };

  stage(0, 0);
  asm volatile("s_waitcnt vmcnt(0)" ::: "memory");
  __syncthreads();

  int cur = 0;
  for (int t = 0; t < 8; t++){
    const int c0 = t << 6;
    bf16x8 wfh[4][2], wfl[4][2];
    #pragma unroll
    for (int a = 0; a < 4; a++){
      long R = (long)(rg * 128 + wx * 64 + a * 16 + n) * 512 + c0 + g * 8;
      wfh[a][0] = *reinterpret_cast<const bf16x8*>(wh + R);
      wfh[a][1] = *reinterpret_cast<const bf16x8*>(wh + R + 32);
    }
    if (rg == 0){
      #pragma unroll
      for (int a = 0; a < 4; a++){
        long R = (long)(wx * 64 + a * 16 + n) * 512 + c0 + g * 8;
        wfl[a][0] = *reinterpret_cast<const bf16x8*>(wl + R);
        wfl[a][1] = *reinterpret_cast<const bf16x8*>(wl + R + 32);
      }
    }
    if (t < 7) stage(cur ^ 1, (t + 1) << 6);
    bf16x8 xh[4][2], xl[4][2];
    const char* buf = lds + cur * 32768;
    #pragma unroll
    for (int m = 0; m < 4; m++){
      int px = wy * 64 + m * 16 + n;
      const char* row = buf + px * 128;
      #pragma unroll
      for (int ks = 0; ks < 2; ks++){
        int off = (((ks << 2) | g) ^ (px & 7)) << 4;
        xh[m][ks] = *reinterpret_cast<const bf16x8*>(row + off);
        xl[m][ks] = *reinterpret_cast<const bf16x8*>(row + 16384 + off);
      }
    }
    __builtin_amdgcn_s_setprio(1);
    if (rg == 0){
      #pragma unroll
      for (int a = 0; a < 4; a++)
        #pragma unroll
        for (int m = 0; m < 4; m++)
          #pragma unroll
          for (int ks = 0; ks < 2; ks++){
            acc[a][m] = __builtin_amdgcn_mfma_f32_16x16x32_bf16(xh[m][ks], wfh[a][ks], acc[a][m], 0, 0, 0);
            acc[a][m] = __builtin_amdgcn_mfma_f32_16x16x32_bf16(xl[m][ks], wfh[a][ks], acc[a][m], 0, 0, 0);
            acc[a][m] = __builtin_amdgcn_mfma_f32_16x16x32_bf16(xh[m][ks], wfl[a][ks], acc[a][m], 0, 0, 0);
          }
    } else {
      #pragma unroll
      for (int a = 0; a < 4; a++)
        #pragma unroll
        for (int m = 0; m < 4; m++)
          #pragma unroll
          for (int ks = 0; ks < 2; ks++){
            acc[a][m] = __builtin_amdgcn_mfma_f32_16x16x32_bf16(wfh[a][ks], xh[m][ks], acc[a][m], 0, 0, 0);
            acc[a][m] = __builtin_amdgcn_mfma_f32_16x16x32_bf16(wfh[a][ks], xl[m][ks], acc[a][m], 0, 0, 0);
          }
    }
    __builtin_amdgcn_s_setprio(0);
    asm volatile("s_waitcnt vmcnt(0)" ::: "memory");
    __syncthreads();
    cur ^= 1;
  }

  if (rg == 0){
    ushort_t* hs = wx ? khi : qhi;
    ushort_t* ls = wx ? klo : qlo;
    const float* bias = wx ? bk : bq;
    #pragma unroll
    for (int a = 0; a < 4; a++){
      float bb = bias[a * 16 + n];
      #pragma unroll
      for (int m = 0; m < 4; m++){
        #pragma unroll
        for (int r4 = 0; r4 < 4; r4++){
          int px = wy * 64 + m * 16 + g * 4 + r4;
          float v = acc[a][m][r4] + bb;
          ushort_t h = f2bf(v);
          ushort_t l = f2bf(v - bf2f(h));
          long ad = (xrow + px) * 64 + a * 16 + n;
          hs[ad] = h;
          ls[ad] = l;
        }
      }
    }
  } else {
    #pragma unroll
    for (int a = 0; a < 4; a++){
      #pragma unroll
      for (int r4 = 0; r4 < 4; r4++){
        int C = (rg - 1) * 128 + wx * 64 + a * 16 + g * 4 + r4;
        float bb = bv[C];
        #pragma unroll
        for (int m = 0; m < 4; m++){
          int px = wy * 64 + m * 16 + n;
          vv[((long)b * NC + C) * HW + i0 + px] = f2bf(acc[a][m][r4] + bb);
        }
      }
    }
  }
}

// ---------------- flash attention: 128 q rows/block, j-split x2, sequential-m ----------------
// 1D grid 256; decode: xcd = wgid&7 -> (jh = xcd>>2, b = xcd&3), qt = wgid>>3.
// All 32 qt-blocks of one (jh,b) land on one XCD (K/V j-half = 2.5MB < 4MB L2).
// Block 512 thr (8 waves): wave w -> rg = w>>1 (32 q rows = 2 m-subtiles), ch = w&1 (256-c half).
// 32 iters over 64-j subtiles. Per iter: for m in {0,1}: QK(24 MFMA, K frags re-read) ->
// softmax -> P roundtrip -> pa[m]; then PV (64 MFMA, V frags shared across m).
// Sequential-m keeps live VGPRs ~100 (acc[2][16]=128 AGPR + <=128 VGPR cap, no spill).
// LDS: [0,32K) K dbuf  [32K,96K) V  [96K,130K) per-wave P scratch fp32 [16][68].
__global__ __launch_bounds__(512, 1) void attn_kernel(
    const ushort_t* __restrict__ qhi, const ushort_t* __restrict__ qlo,
    const ushort_t* __restrict__ khi, const ushort_t* __restrict__ klo,
    const ushort_t* __restrict__ vv,
    ushort_t* __restrict__ p0, ushort_t* __restrict__ p1,
    float* __restrict__ mbuf, float* __restrict__ lbuf)
{
  extern __shared__ char smem[];
  const int wgid = blockIdx.x;
  const int xcd = wgid & 7;
  const int jh = xcd >> 2;
  const int b  = xcd & 3;
  const int qt = wgid >> 3;
  const int tid = threadIdx.x;
  const int w = tid >> 6;
  const int lane = tid & 63;
  const int g = lane >> 4, n = lane & 15;
  const int rg = w >> 1, ch = w & 1;
  const int i0w = qt * 128 + rg * 32;
  const int c0w = ch * 256;
  const int jbase = jh * 2048;

  float* psw = (float*)(smem + 98304) + w * (16 * 68);

  const int kj = tid >> 3;
  const int kdblk = (tid & 7) ^ (kj & 7);
  const long kgbase = ((long)b * HW + kj) * 64 + kdblk * 8;

  auto stageK = [&](int bsel, int j0){
    char* dst = smem + bsel * 16384 + (w << 10);
    GLOAD_LDS(khi + kgbase + (long)j0 * 64, dst);
    GLOAD_LDS(klo + kgbase + (long)j0 * 64, dst + 8192);
  };
  auto stageV = [&](int j0){
    #pragma unroll
    for (int r = 0; r < 8; r++){
      int ss = (r << 9) | tid;
      int c = ss >> 3;
      int jblk = (ss & 7) ^ (c & 7);
      long goff = (long)b * (NC * HW) + (long)c * HW + j0 + jblk * 8;
      GLOAD_LDS(vv + goff, smem + 32768 + (r << 13) + (w << 10));
    }
  };

  bf16x8 aqh[2][2], aql[2][2];
  #pragma unroll
  for (int m = 0; m < 2; m++){
    long qb = ((long)b * HW + i0w + m * 16 + n) * 64 + g * 8;
    aqh[m][0] = *reinterpret_cast<const bf16x8*>(qhi + qb);
    aqh[m][1] = *reinterpret_cast<const bf16x8*>(qhi + qb + 32);
    aql[m][0] = *reinterpret_cast<const bf16x8*>(qlo + qb);
    aql[m][1] = *reinterpret_cast<const bf16x8*>(qlo + qb + 32);
  }

  f32x4 acc[2][16];
  #pragma unroll
  for (int m = 0; m < 2; m++)
    #pragma unroll
    for (int t = 0; t < 16; t++) acc[m][t] = (f32x4){0.f, 0.f, 0.f, 0.f};
  float mrow[2][4], lrow[2][4];
  #pragma unroll
  for (int m = 0; m < 2; m++)
    #pragma unroll
    for (int r = 0; r < 4; r++){ mrow[m][r] = -1e30f; lrow[m][r] = 0.f; }

  stageK(0, jbase);
  stageV(jbase);
  asm volatile("s_waitcnt vmcnt(0)" ::: "memory");
  __syncthreads();

  int cur = 0;
  for (int t = 0; t < 32; t++){
    // 1. prefetch K[t+1] into the other K buffer (stays in flight across QK/softmax)
    stageK(cur ^ 1, jbase + ((t + 1) & 31) * 64);
    // 2. per-m: QK (K frags re-read from LDS; sv[4] only 16 VGPRs live) -> softmax -> pa[m]
    bf16x8 pa[2][2];
    #pragma unroll
    for (int m = 0; m < 2; m++){
      f32x4 sv[4];
      {
        const char* kb0 = smem + cur * 16384;
        __builtin_amdgcn_s_setprio(1);
        #pragma unroll
        for (int nt = 0; nt < 4; nt++){
          int jl = nt * 16 + n;
          const char* kb = kb0 + jl * 128;
          int x0 = (g ^ (jl & 7)) << 4;
          int x1 = ((g + 4) ^ (jl & 7)) << 4;
          bf16x8 bh0 = *(const bf16x8*)(kb + x0);
          bf16x8 bh1 = *(const bf16x8*)(kb + x1);
          bf16x8 bl0 = *(const bf16x8*)(kb + 8192 + x0);
          bf16x8 bl1 = *(const bf16x8*)(kb + 8192 + x1);
          f32x4 s = (f32x4){0.f, 0.f, 0.f, 0.f};
          s = __builtin_amdgcn_mfma_f32_16x16x32_bf16(aqh[m][0], bh0, s, 0, 0, 0);
          s = __builtin_amdgcn_mfma_f32_16x16x32_bf16(aqh[m][1], bh1, s, 0, 0, 0);
          s = __builtin_amdgcn_mfma_f32_16x16x32_bf16(aql[m][0], bh0, s, 0, 0, 0);
          s = __builtin_amdgcn_mfma_f32_16x16x32_bf16(aql[m][1], bh1, s, 0, 0, 0);
          s = __builtin_amdgcn_mfma_f32_16x16x32_bf16(aqh[m][0], bl0, s, 0, 0, 0);
          s = __builtin_amdgcn_mfma_f32_16x16x32_bf16(aqh[m][1], bl1, s, 0, 0, 0);
          sv[nt] = s;
        }
        __builtin_amdgcn_s_setprio(0);
      }
      float mnew[4]; int upd = 0;
      #pragma unroll
      for (int r = 0; r < 4; r++){
        float tmx = fmaxf(fmaxf(sv[0][r], sv[1][r]), fmaxf(sv[2][r], sv[3][r]));
        tmx = fmaxf(tmx, __shfl_xor(tmx, 1));
        tmx = fmaxf(tmx, __shfl_xor(tmx, 2));
        tmx = fmaxf(tmx, __shfl_xor(tmx, 4));
        tmx = fmaxf(tmx, __shfl_xor(tmx, 8));
        mnew[r] = fmaxf(mrow[m][r], tmx);
        upd |= (mnew[r] > mrow[m][r]) ? 1 : 0;
      }
      if (__any(upd)){
        #pragma unroll
        for (int r = 0; r < 4; r++){
          float sc = __expf(mrow[m][r] - mnew[r]);
          lrow[m][r] *= sc;
          mrow[m][r] = mnew[r];
          #pragma unroll
          for (int ct = 0; ct < 16; ct++) acc[m][ct][r] *= sc;
        }
      }
      float p[4][4];
      #pragma unroll
      for (int nt = 0; nt < 4; nt++)
        #pragma unroll
        for (int r = 0; r < 4; r++)
          p[nt][r] = __expf(sv[nt][r] - mrow[m][r]);
      #pragma unroll
      for (int r = 0; r < 4; r++){
        float rs = (p[0][r] + p[1][r]) + (p[2][r] + p[3][r]);
        rs += __shfl_xor(rs, 1);
        rs += __shfl_xor(rs, 2);
        rs += __shfl_xor(rs, 4);
        rs += __shfl_xor(rs, 8);
        lrow[m][r] += rs;
      }
      #pragma unroll
      for (int nt = 0; nt < 4; nt++)
        #pragma unroll
        for (int r = 0; r < 4; r++)
          psw[(g * 4 + r) * 68 + nt * 16 + n] = p[nt][r];
      #pragma unroll
      for (int ks = 0; ks < 2; ks++){
        const f32x4* pr = reinterpret_cast<const f32x4*>(&psw[n * 68 + ks * 32 + g * 8]);
        f32x4 f0 = pr[0], f1 = pr[1];
        bf16x8 tt;
        tt[0] = (short)f2bf(f0[0]); tt[1] = (short)f2bf(f0[1]);
        tt[2] = (short)f2bf(f0[2]); tt[3] = (short)f2bf(f0[3]);
        tt[4] = (short)f2bf(f1[0]); tt[5] = (short)f2bf(f1[1]);
        tt[6] = (short)f2bf(f1[2]); tt[7] = (short)f2bf(f1[3]);
        pa[m][ks] = tt;
      }
    }
    // 3. wait V landed (K prefetch still in flight), sync all waves
    asm volatile("s_waitcnt vmcnt(2)" ::: "memory");
    __syncthreads();
    // 4. PV from V LDS tile; each V fragment serves both m-subtiles
    {
      const char* vb0 = smem + 32768 + (c0w + n) * 128;
      __builtin_amdgcn_s_setprio(1);
      #pragma unroll
      for (int ct = 0; ct < 16; ct++){
        int cl = c0w + ct * 16 + n;
        const char* vb = vb0 + ct * 2048;
        int x0 = (g ^ (cl & 7)) << 4;
        int x1 = ((g + 4) ^ (cl & 7)) << 4;
        bf16x8 bv0 = *(const bf16x8*)(vb + x0);
        bf16x8 bv1 = *(const bf16x8*)(vb + x1);
        #pragma unroll
        for (int m = 0; m < 2; m++){
          acc[m][ct] = __builtin_amdgcn_mfma_f32_16x16x32_bf16(pa[m][0], bv0, acc[m][ct], 0, 0, 0);
          acc[m][ct] = __builtin_amdgcn_mfma_f32_16x16x32_bf16(pa[m][1], bv1, acc[m][ct], 0, 0, 0);
        }
      }
      __builtin_amdgcn_s_setprio(0);
    }
    // 5. drain K prefetch, sync (all waves done with V buffer), refill V
    asm volatile("s_waitcnt vmcnt(0)" ::: "memory");
    __syncthreads();
    if (t < 31) stageV(jbase + (t + 1) * 64);
    cur ^= 1;
  }

  // epilogue: unnormalized partial bf16 [b][i][c] + per-row (m,l)
  ushort_t* pd = jh ? p1 : p0;
  #pragma unroll
  for (int m = 0; m < 2; m++){
    #pragma unroll
    for (int ct = 0; ct < 16; ct++){
      #pragma unroll
      for (int r = 0; r < 4; r++){
        int i = i0w + m * 16 + g * 4 + r;
        int c = c0w + ct * 16 + n;
        pd[((long)b * HW + i) * NC + c] = f2bf(acc[m][ct][r]);
      }
    }
  }
  if (ch == 0 && n == 0){
    #pragma unroll
    for (int m = 0; m < 2; m++)
      #pragma unroll
      for (int r = 0; r < 4; r++){
        int gi = b * HW + i0w + m * 16 + g * 4 + r;
        mbuf[jh * (NB * HW) + gi] = mrow[m][r];
        lbuf[jh * (NB * HW) + gi] = lrow[m][r];
      }
  }
}

// ---------------- combine halves + epilogue: out = gamma * O + x ----------------
__global__ __launch_bounds__(256) void comb_kernel(
    const ushort_t* __restrict__ p0, const ushort_t* __restrict__ p1,
    const float* __restrict__ mbuf, const float* __restrict__ lbuf,
    const float* __restrict__ x, const float* __restrict__ gamma,
    float* __restrict__ out)
{
  const int it = blockIdx.x;
  const int ct = blockIdx.y;
  const int b  = blockIdx.z;
  const int i0 = it * 64, c0 = ct * 64;
  const int tid = threadIdx.x;
  const int tx = tid & 63, ty = tid >> 6;
  __shared__ float ts[64][65];
  __shared__ float f0s[64], f1s[64];
  const float gm = gamma[0];
  if (tid < 64){
    int gi = b * HW + i0 + tid;
    float m0 = mbuf[gi], m1 = mbuf[NB * HW + gi];
    float l0 = lbuf[gi], l1 = lbuf[NB * HW + gi];
    float M = fmaxf(m0, m1);
    float w0 = __expf(m0 - M), w1 = __expf(m1 - M);
    float rden = 1.f / (w0 * l0 + w1 * l1);
    f0s[tid] = w0 * rden;
    f1s[tid] = w1 * rden;
  }
  __syncthreads();
  #pragma unroll
  for (int u = 0; u < 16; u++){
    int il = ty * 16 + u;
    long pidx = ((long)b * HW + i0 + il) * NC + c0 + tx;
    ts[il][tx] = f0s[il] * bf2f(p0[pidx]) + f1s[il] * bf2f(p1[pidx]);
  }
  __syncthreads();
  #pragma unroll
  for (int u = 0; u < 16; u++){
    int cl = ty * 16 + u;
    long idx = ((long)b * NC + c0 + cl) * HW + i0 + tx;
    out[idx] = fmaf(gm, ts[tx][cl], x[idx]);
  }
}

extern "C" void kernel_launch(void* const* d_in, const int* in_sizes, int n_in,
                              void* d_out, int out_size, void* d_ws, size_t ws_size,
                              hipStream_t stream)
{
  const float* x  = (const float*)d_in[0];
  const float* Wq = (const float*)d_in[1];
  const float* bq = (const float*)d_in[2];
  const float* Wk = (const float*)d_in[3];
  const float* bk = (const float*)d_in[4];
  const float* Wv = (const float*)d_in[5];
  const float* bv = (const float*)d_in[6];
  const float* gamma = (const float*)d_in[7];
  float* out = (float*)d_out;

  char* ws = (char*)d_ws;
  const size_t MB = 1024 * 1024;
  ushort_t* xth = (ushort_t*)(ws);                 // 16 MB, reused as partial0
  ushort_t* xtl = (ushort_t*)(ws + 16 * MB);       // 16 MB, reused as partial1
  ushort_t* wh  = (ushort_t*)(ws + 32 * MB);       // 640 KB
  ushort_t* wl  = (ushort_t*)(ws + 32 * MB + 655360);  // 128 KB
  ushort_t* qhi = (ushort_t*)(ws + 33 * MB);       // 2 MB each
  ushort_t* qlo = (ushort_t*)(ws + 35 * MB);
  ushort_t* khi = (ushort_t*)(ws + 37 * MB);
  ushort_t* klo = (ushort_t*)(ws + 39 * MB);
  ushort_t* vv  = (ushort_t*)(ws + 41 * MB);       // 16 MB
  float*    mbuf = (float*)(ws + 57 * MB);         // 128 KB
  float*    lbuf = (float*)(ws + 57 * MB + 131072);// 128 KB
  ushort_t* part0 = xth;   // alias: xt dead after gemm
  ushort_t* part1 = xtl;

  wsplit_kernel<<<dim3(160), dim3(256), 0, stream>>>(Wq, Wk, Wv, wh, wl);
  split_kernel<<<dim3(64, 8, NB), dim3(256), 0, stream>>>(x, xth, xtl);

  const int GSMEM = 65536;
  hipFuncSetAttribute((const void*)gemm_kernel,
                      hipFuncAttributeMaxDynamicSharedMemorySize, GSMEM);
  gemm_kernel<<<dim3(32, 5, NB), dim3(256), GSMEM, stream>>>(
      xth, xtl, wh, wl, bq, bk, bv, qhi, qlo, khi, klo, vv);

  const int ASMEM = 133120;  // 32K K dbuf + 64K V + 34K P scratch
  hipFuncSetAttribute((const void*)attn_kernel,
                      hipFuncAttributeMaxDynamicSharedMemorySize, ASMEM);
  attn_kernel<<<dim3(256), dim3(512), ASMEM, stream>>>(
      qhi, qlo, khi, klo, vv, part0, part1, mbuf, lbuf);

  comb_kernel<<<dim3(64, 8, NB), dim3(256), 0, stream>>>(
      part0, part1, mbuf, lbuf, x, gamma, out);
}

// Round 7
// 220.549 us; speedup vs baseline: 1.6440x; 1.6174x over previous
//
#include <hip/hip_runtime.h>
#include <hip/hip_bf16.h>

#define HW 4096
#define NC 512
#define NB 4

typedef float f32x4 __attribute__((ext_vector_type(4)));
typedef float f32x16 __attribute__((ext_vector_type(16)));
typedef short bf16x8 __attribute__((ext_vector_type(8)));
typedef unsigned int u32;
typedef u32 u32x4 __attribute__((ext_vector_type(4)));
typedef unsigned short ushort_t;

#define GLOAD_LDS(g, s) __builtin_amdgcn_global_load_lds((const __attribute__((address_space(1))) void*)(g), (__attribute__((address_space(3))) void*)(s), 16, 0, 0)

__device__ __forceinline__ unsigned short f2bf(float f){
  unsigned int u = __builtin_bit_cast(unsigned int, f);
  u += 0x7FFFu + ((u >> 16) & 1u);
  return (unsigned short)(u >> 16);
}
__device__ __forceinline__ float bf2f(unsigned short h){
  unsigned int u = ((unsigned int)h) << 16;
  return __builtin_bit_cast(float, u);
}

// ---------------- W -> bf16 hi (+lo for q/k rows 0..127) ----------------
__global__ __launch_bounds__(256) void wsplit_kernel(
    const float* __restrict__ Wq, const float* __restrict__ Wk,
    const float* __restrict__ Wv, ushort_t* __restrict__ wh, ushort_t* __restrict__ wl)
{
  long e = ((long)blockIdx.x * 256 + threadIdx.x) * 8;
  int r = (int)(e >> 9), c = (int)(e & 511);
  const float* src = (r < 64)  ? Wq + (long)r * 512 + c
                   : (r < 128) ? Wk + (long)(r - 64) * 512 + c
                               : Wv + (long)(r - 128) * 512 + c;
  f32x4 v0 = *reinterpret_cast<const f32x4*>(src);
  f32x4 v1 = *reinterpret_cast<const f32x4*>(src + 4);
  ushort_t h[8], l[8];
  #pragma unroll
  for (int j = 0; j < 4; j++){ h[j] = f2bf(v0[j]); l[j] = f2bf(v0[j] - bf2f(h[j])); }
  #pragma unroll
  for (int j = 0; j < 4; j++){ h[4+j] = f2bf(v1[j]); l[4+j] = f2bf(v1[j] - bf2f(h[4+j])); }
  *reinterpret_cast<bf16x8*>(wh + e) = *reinterpret_cast<bf16x8*>(h);
  if (r < 128) *reinterpret_cast<bf16x8*>(wl + e) = *reinterpret_cast<bf16x8*>(l);
}

// ---------------- x [b][c][px] fp32 -> xt hi/lo [b][px][c] bf16 ----------------
__global__ __launch_bounds__(256) void split_kernel(
    const float* __restrict__ x, ushort_t* __restrict__ xth, ushort_t* __restrict__ xtl)
{
  const int i0 = blockIdx.x * 64;
  const int c0 = blockIdx.y * 64;
  const int b  = blockIdx.z;
  const int tid = threadIdx.x;
  const int tx = tid & 63, ty = tid >> 6;
  __shared__ float ts[64][65];
  #pragma unroll
  for (int u = 0; u < 16; u++){
    int cl = ty * 16 + u;
    ts[cl][tx] = x[((long)b * NC + c0 + cl) * HW + i0 + tx];
  }
  __syncthreads();
  const int px = tid >> 2;
  const int cs = (tid & 3) * 16;
  ushort_t h[16], l[16];
  #pragma unroll
  for (int e = 0; e < 16; e++){
    float v = ts[cs + e][px];
    h[e] = f2bf(v);
    l[e] = f2bf(v - bf2f(h[e]));
  }
  long base = ((long)b * HW + i0 + px) * 512 + c0 + cs;
  *reinterpret_cast<bf16x8*>(xth + base)     = *reinterpret_cast<bf16x8*>(h);
  *reinterpret_cast<bf16x8*>(xth + base + 8) = *reinterpret_cast<bf16x8*>(h + 8);
  *reinterpret_cast<bf16x8*>(xtl + base)     = *reinterpret_cast<bf16x8*>(l);
  *reinterpret_cast<bf16x8*>(xtl + base + 8) = *reinterpret_cast<bf16x8*>(l + 8);
}

// ---------------- MFMA projection GEMM (unchanged from round 3) ----------------
__global__ __launch_bounds__(256) void gemm_kernel(
    const ushort_t* __restrict__ xth, const ushort_t* __restrict__ xtl,
    const ushort_t* __restrict__ wh, const ushort_t* __restrict__ wl,
    const float* __restrict__ bq, const float* __restrict__ bk, const float* __restrict__ bv,
    ushort_t* __restrict__ qhi, ushort_t* __restrict__ qlo,
    ushort_t* __restrict__ khi, ushort_t* __restrict__ klo,
    ushort_t* __restrict__ vv)
{
  extern __shared__ char lds[];
  const int it = blockIdx.x;
  const int rg = blockIdx.y;
  const int b  = blockIdx.z;
  const int i0 = it * 128;
  const int tid = threadIdx.x;
  const int w = tid >> 6;
  const int lane = tid & 63;
  const int g = lane >> 4, n = lane & 15;
  const int wy = w >> 1, wx = w & 1;

  f32x4 acc[4][4];
  #pragma unroll
  for (int a = 0; a < 4; a++)
    #pragma unroll
    for (int m = 0; m < 4; m++) acc[a][m] = (f32x4){0.f, 0.f, 0.f, 0.f};

  const long xrow = (long)b * HW + i0;

  auto stage = [&](int bsel, int c0s){
    char* dbase = lds + bsel * 32768 + (w << 10);
    #pragma unroll
    for (int u = 0; u < 4; u++){
      int idx = (u << 8) | tid;
      int px = idx >> 3;
      int chs = (idx & 7) ^ (px & 7);
      long go = (xrow + px) * 512 + c0s + chs * 8;
      GLOAD_LDS(xth + go, dbase + (u << 12));
      GLOAD_LDS(xtl + go, dbase + 16384 + (u << 12));
    }
  };

  stage(0, 0);
  asm volatile("s_waitcnt vmcnt(0)" ::: "memory");
  __syncthreads();

  int cur = 0;
  for (int t = 0; t < 8; t++){
    const int c0 = t << 6;
    bf16x8 wfh[4][2], wfl[4][2];
    #pragma unroll
    for (int a = 0; a < 4; a++){
      long R = (long)(rg * 128 + wx * 64 + a * 16 + n) * 512 + c0 + g * 8;
      wfh[a][0] = *reinterpret_cast<const bf16x8*>(wh + R);
      wfh[a][1] = *reinterpret_cast<const bf16x8*>(wh + R + 32);
    }
    if (rg == 0){
      #pragma unroll
      for (int a = 0; a < 4; a++){
        long R = (long)(wx * 64 + a * 16 + n) * 512 + c0 + g * 8;
        wfl[a][0] = *reinterpret_cast<const bf16x8*>(wl + R);
        wfl[a][1] = *reinterpret_cast<const bf16x8*>(wl + R + 32);
      }
    }
    if (t < 7) stage(cur ^ 1, (t + 1) << 6);
    bf16x8 xh[4][2], xl[4][2];
    const char* buf = lds + cur * 32768;
    #pragma unroll
    for (int m = 0; m < 4; m++){
      int px = wy * 64 + m * 16 + n;
      const char* row = buf + px * 128;
      #pragma unroll
      for (int ks = 0; ks < 2; ks++){
        int off = (((ks << 2) | g) ^ (px & 7)) << 4;
        xh[m][ks] = *reinterpret_cast<const bf16x8*>(row + off);
        xl[m][ks] = *reinterpret_cast<const bf16x8*>(row + 16384 + off);
      }
    }
    __builtin_amdgcn_s_setprio(1);
    if (rg == 0){
      #pragma unroll
      for (int a = 0; a < 4; a++)
        #pragma unroll
        for (int m = 0; m < 4; m++)
          #pragma unroll
          for (int ks = 0; ks < 2; ks++){
            acc[a][m] = __builtin_amdgcn_mfma_f32_16x16x32_bf16(xh[m][ks], wfh[a][ks], acc[a][m], 0, 0, 0);
            acc[a][m] = __builtin_amdgcn_mfma_f32_16x16x32_bf16(xl[m][ks], wfh[a][ks], acc[a][m], 0, 0, 0);
            acc[a][m] = __builtin_amdgcn_mfma_f32_16x16x32_bf16(xh[m][ks], wfl[a][ks], acc[a][m], 0, 0, 0);
          }
    } else {
      #pragma unroll
      for (int a = 0; a < 4; a++)
        #pragma unroll
        for (int m = 0; m < 4; m++)
          #pragma unroll
          for (int ks = 0; ks < 2; ks++){
            acc[a][m] = __builtin_amdgcn_mfma_f32_16x16x32_bf16(wfh[a][ks], xh[m][ks], acc[a][m], 0, 0, 0);
            acc[a][m] = __builtin_amdgcn_mfma_f32_16x16x32_bf16(wfh[a][ks], xl[m][ks], acc[a][m], 0, 0, 0);
          }
    }
    __builtin_amdgcn_s_setprio(0);
    asm volatile("s_waitcnt vmcnt(0)" ::: "memory");
    __syncthreads();
    cur ^= 1;
  }

  if (rg == 0){
    ushort_t* hs = wx ? khi : qhi;
    ushort_t* ls = wx ? klo : qlo;
    const float* bias = wx ? bk : bq;
    #pragma unroll
    for (int a = 0; a < 4; a++){
      float bb = bias[a * 16 + n];
      #pragma unroll
      for (int m = 0; m < 4; m++){
        #pragma unroll
        for (int r4 = 0; r4 < 4; r4++){
          int px = wy * 64 + m * 16 + g * 4 + r4;
          float v = acc[a][m][r4] + bb;
          ushort_t h = f2bf(v);
          ushort_t l = f2bf(v - bf2f(h));
          long ad = (xrow + px) * 64 + a * 16 + n;
          hs[ad] = h;
          ls[ad] = l;
        }
      }
    }
  } else {
    #pragma unroll
    for (int a = 0; a < 4; a++){
      #pragma unroll
      for (int r4 = 0; r4 < 4; r4++){
        int C = (rg - 1) * 128 + wx * 64 + a * 16 + g * 4 + r4;
        float bb = bv[C];
        #pragma unroll
        for (int m = 0; m < 4; m++){
          int px = wy * 64 + m * 16 + n;
          vv[((long)b * NC + C) * HW + i0 + px] = f2bf(acc[a][m][r4] + bb);
        }
      }
    }
  }
}

// ---------------- flash attention: swapped-QK 32x32, in-register softmax/P ----------------
// 1D grid 256; decode: xcd = wgid&7 -> (jh = xcd>>2, b = xcd&3), qt = wgid>>3.
// Block 512 thr (8 waves): wave w -> rg = w>>1 (32 q rows), ch = w&1 (256-c half).
// Per lane: q = i0w + (lane&31) (ONE q row -> softmax state is scalar per lane).
// 32 iters over 64-j subtiles of the 2048-j half.
// QK: mfma(A=K, B=Q) 32x32x16 -> S[j(regs), q(lanes)]. P repacked to MFMA frags
// via cvt_pk_bf16 + shfl_xor(32) (no LDS roundtrip). PV: mfma(A=V, B=P) ->
// acc[c(regs), q(lanes)] -> coalesced [c][i] partial store.
// LDS: [0,32K) K dbuf (16KB each: hi 8K + lo 8K, [64j][64d] 128B rows XOR-8)
//      [32K,96K) V single buffer ([512c][64j] 128B rows XOR-8)
__global__ __launch_bounds__(512, 1) void attn_kernel(
    const ushort_t* __restrict__ qhi, const ushort_t* __restrict__ qlo,
    const ushort_t* __restrict__ khi, const ushort_t* __restrict__ klo,
    const ushort_t* __restrict__ vv,
    ushort_t* __restrict__ p0, ushort_t* __restrict__ p1,
    float* __restrict__ mbuf, float* __restrict__ lbuf)
{
  extern __shared__ char smem[];
  const int wgid = blockIdx.x;
  const int xcd = wgid & 7;
  const int jh = xcd >> 2;
  const int b  = xcd & 3;
  const int qt = wgid >> 3;
  const int tid = threadIdx.x;
  const int w = tid >> 6;
  const int lane = tid & 63;
  const int q32 = lane & 31;      // q-local (QK/PV cols), j-row (QK A), c-row (PV A)
  const int hh = lane >> 5;
  const int rg = w >> 1, ch = w & 1;
  const int i0w = qt * 128 + rg * 32;
  const int c0w = ch * 256;
  const int jbase = jh * 2048;

  // K staging (identical to proven layout): LDS[row][chunk p] = d-block (p ^ (row&7))
  const int kj = tid >> 3;
  const int kdblk = (tid & 7) ^ (kj & 7);
  const long kgbase = ((long)b * HW + kj) * 64 + kdblk * 8;

  auto stageK = [&](int bsel, int j0){
    char* dst = smem + bsel * 16384 + (w << 10);
    GLOAD_LDS(khi + kgbase + (long)j0 * 64, dst);
    GLOAD_LDS(klo + kgbase + (long)j0 * 64, dst + 8192);
  };
  auto stageV = [&](int j0){
    #pragma unroll
    for (int r = 0; r < 8; r++){
      int ss = (r << 9) | tid;
      int c = ss >> 3;
      int jblk = (ss & 7) ^ (c & 7);
      long goff = (long)b * (NC * HW) + (long)c * HW + j0 + jblk * 8;
      GLOAD_LDS(vv + goff, smem + 32768 + (r << 13) + (w << 10));
    }
  };

  // Q fragments (B-operand): col q = lane&31, k(d) = chain*16 + hh*8 + e
  bf16x8 aqh[4], aql[4];
  #pragma unroll
  for (int c = 0; c < 4; c++){
    long qb = ((long)b * HW + i0w + q32) * 64 + c * 16 + hh * 8;
    aqh[c] = *reinterpret_cast<const bf16x8*>(qhi + qb);
    aql[c] = *reinterpret_cast<const bf16x8*>(qlo + qb);
  }

  f32x16 acc[8];
  #pragma unroll
  for (int ct = 0; ct < 8; ct++)
    #pragma unroll
    for (int r = 0; r < 16; r++) acc[ct][r] = 0.f;
  float mrow = -1e30f, lrow = 0.f;

  stageK(0, jbase);
  stageV(jbase);
  asm volatile("s_waitcnt vmcnt(0)" ::: "memory");
  __syncthreads();

  int cur = 0;
  for (int t = 0; t < 32; t++){
    // 1. prefetch K[t+1] (2 loads, stay in flight across QK+softmax)
    stageK(cur ^ 1, jbase + ((t + 1) & 31) * 64);
    // 2. QK swapped: S[j, q] (3-term hi/lo), two 32-j tiles
    f32x16 sv[2];
    {
      const char* kb0 = smem + cur * 16384;
      __builtin_amdgcn_s_setprio(1);
      #pragma unroll
      for (int jt = 0; jt < 2; jt++){
        int jrow = jt * 32 + q32;
        const char* krow = kb0 + jrow * 128;
        int r7 = jrow & 7;
        f32x16 s;
        #pragma unroll
        for (int r = 0; r < 16; r++) s[r] = 0.f;
        #pragma unroll
        for (int c = 0; c < 4; c++){
          int off = (((c << 1) | hh) ^ r7) << 4;
          bf16x8 kh = *(const bf16x8*)(krow + off);
          bf16x8 kl = *(const bf16x8*)(krow + 8192 + off);
          s = __builtin_amdgcn_mfma_f32_32x32x16_bf16(kh, aqh[c], s, 0, 0, 0);
          s = __builtin_amdgcn_mfma_f32_32x32x16_bf16(kh, aql[c], s, 0, 0, 0);
          s = __builtin_amdgcn_mfma_f32_32x32x16_bf16(kl, aqh[c], s, 0, 0, 0);
        }
        sv[jt] = s;
      }
      __builtin_amdgcn_s_setprio(0);
    }
    // 3. in-lane softmax (q = lane&31; full row = own 32 + partner-half 32)
    {
      f32x16 mx;
      #pragma unroll
      for (int r = 0; r < 16; r++) mx[r] = fmaxf(sv[0][r], sv[1][r]);
      float m8[8];
      #pragma unroll
      for (int r = 0; r < 8; r++) m8[r] = fmaxf(mx[r], mx[r + 8]);
      float m4a = fmaxf(m8[0], m8[4]), m4b = fmaxf(m8[1], m8[5]);
      float m4c = fmaxf(m8[2], m8[6]), m4d = fmaxf(m8[3], m8[7]);
      float tmx = fmaxf(fmaxf(m4a, m4b), fmaxf(m4c, m4d));
      tmx = fmaxf(tmx, __shfl_xor(tmx, 32));
      // defer-max (T13): rescale only when growth exceeds threshold
      if (__any(tmx > mrow + 8.f)){
        float mnew = fmaxf(mrow, tmx);
        float sc = __expf(mrow - mnew);
        lrow *= sc;
        #pragma unroll
        for (int ct = 0; ct < 8; ct++)
          #pragma unroll
          for (int r = 0; r < 16; r++) acc[ct][r] *= sc;
        mrow = mnew;
      }
    }
    // 4. P = exp(S - m), row-sum, pack to bf16 MFMA fragments in-register
    bf16x8 pa[4];
    {
      #pragma unroll
      for (int jt = 0; jt < 2; jt++)
        #pragma unroll
        for (int r = 0; r < 16; r++) sv[jt][r] = __expf(sv[jt][r] - mrow);
      float rs = 0.f;
      #pragma unroll
      for (int r = 0; r < 16; r++) rs += sv[0][r] + sv[1][r];
      rs += __shfl_xor(rs, 32);
      lrow += rs;
      #pragma unroll
      for (int jt = 0; jt < 2; jt++){
        u32 pk[8];
        #pragma unroll
        for (int i = 0; i < 8; i++){
          float a = sv[jt][2 * i], bb = sv[jt][2 * i + 1];
          u32 d;
          asm("v_cvt_pk_bf16_f32 %0, %1, %2" : "=v"(d) : "v"(a), "v"(bb));
          pk[i] = d;
        }
        #pragma unroll
        for (int cc = 0; cc < 2; cc++){
          u32 x0 = __shfl_xor(pk[4 * cc + 0], 32);
          u32 x1 = __shfl_xor(pk[4 * cc + 1], 32);
          u32 x2 = __shfl_xor(pk[4 * cc + 2], 32);
          u32 x3 = __shfl_xor(pk[4 * cc + 3], 32);
          u32x4 wv;
          wv[0] = hh ? x2 : pk[4 * cc + 0];
          wv[1] = hh ? x3 : pk[4 * cc + 1];
          wv[2] = hh ? pk[4 * cc + 2] : x0;
          wv[3] = hh ? pk[4 * cc + 3] : x1;
          pa[jt * 2 + cc] = __builtin_bit_cast(bf16x8, wv);
        }
      }
    }
    // 5. wait V landed (K prefetch still in flight), sync
    asm volatile("s_waitcnt vmcnt(2)" ::: "memory");
    __syncthreads();
    // 6. PV: mfma(A=V, B=P) -> acc[c(regs), q(lanes)]
    {
      const char* vb = smem + 32768;
      __builtin_amdgcn_s_setprio(1);
      #pragma unroll
      for (int ct = 0; ct < 8; ct++){
        int row = c0w + ct * 32 + q32;
        const char* vrow = vb + row * 128;
        int r7 = row & 7;
        #pragma unroll
        for (int c = 0; c < 4; c++){
          int off = (((c << 1) | hh) ^ r7) << 4;
          bf16x8 vf = *(const bf16x8*)(vrow + off);
          acc[ct] = __builtin_amdgcn_mfma_f32_32x32x16_bf16(vf, pa[c], acc[ct], 0, 0, 0);
        }
      }
      __builtin_amdgcn_s_setprio(0);
    }
    // 7. drain K prefetch, sync (all waves done with V), refill V
    asm volatile("s_waitcnt vmcnt(0)" ::: "memory");
    __syncthreads();
    if (t < 31) stageV(jbase + (t + 1) * 64);
    cur ^= 1;
  }

  // epilogue: unnormalized partial bf16, [b][c][i] layout (coalesced in i)
  ushort_t* pd = jh ? p1 : p0;
  const int i = i0w + q32;
  #pragma unroll
  for (int ct = 0; ct < 8; ct++){
    #pragma unroll
    for (int r = 0; r < 16; r++){
      int c = c0w + ct * 32 + (r & 3) + 8 * (r >> 2) + 4 * hh;
      pd[((long)b * NC + c) * HW + i] = f2bf(acc[ct][r]);
    }
  }
  if (ch == 0 && lane < 32){
    int gi = b * HW + i0w + lane;
    mbuf[jh * (NB * HW) + gi] = mrow;
    lbuf[jh * (NB * HW) + gi] = lrow;
  }
}

// ---------------- combine halves + epilogue: out = gamma * O + x ----------------
// partials now [b][c][i]: pure elementwise, no transpose needed.
__global__ __launch_bounds__(256) void comb_kernel(
    const ushort_t* __restrict__ p0, const ushort_t* __restrict__ p1,
    const float* __restrict__ mbuf, const float* __restrict__ lbuf,
    const float* __restrict__ x, const float* __restrict__ gamma,
    float* __restrict__ out)
{
  const int it = blockIdx.x;
  const int ct = blockIdx.y;
  const int b  = blockIdx.z;
  const int i0 = it * 64, c0 = ct * 64;
  const int tid = threadIdx.x;
  const int tx = tid & 63, ty = tid >> 6;
  __shared__ float f0s[64], f1s[64];
  const float gm = gamma[0];
  if (tid < 64){
    int gi = b * HW + i0 + tid;
    float m0 = mbuf[gi], m1 = mbuf[NB * HW + gi];
    float l0 = lbuf[gi], l1 = lbuf[NB * HW + gi];
    float M = fmaxf(m0, m1);
    float w0 = __expf(m0 - M), w1 = __expf(m1 - M);
    float rden = 1.f / (w0 * l0 + w1 * l1);
    f0s[tid] = w0 * rden;
    f1s[tid] = w1 * rden;
  }
  __syncthreads();
  #pragma unroll
  for (int u = 0; u < 16; u++){
    int cl = ty * 16 + u;
    long idx = ((long)b * NC + c0 + cl) * HW + i0 + tx;
    float o = f0s[tx] * bf2f(p0[idx]) + f1s[tx] * bf2f(p1[idx]);
    out[idx] = fmaf(gm, o, x[idx]);
  }
}

extern "C" void kernel_launch(void* const* d_in, const int* in_sizes, int n_in,
                              void* d_out, int out_size, void* d_ws, size_t ws_size,
                              hipStream_t stream)
{
  const float* x  = (const float*)d_in[0];
  const float* Wq = (const float*)d_in[1];
  const float* bq = (const float*)d_in[2];
  const float* Wk = (const float*)d_in[3];
  const float* bk = (const float*)d_in[4];
  const float* Wv = (const float*)d_in[5];
  const float* bv = (const float*)d_in[6];
  const float* gamma = (const float*)d_in[7];
  float* out = (float*)d_out;

  char* ws = (char*)d_ws;
  const size_t MB = 1024 * 1024;
  ushort_t* xth = (ushort_t*)(ws);                 // 16 MB, reused as partial0
  ushort_t* xtl = (ushort_t*)(ws + 16 * MB);       // 16 MB, reused as partial1
  ushort_t* wh  = (ushort_t*)(ws + 32 * MB);       // 640 KB
  ushort_t* wl  = (ushort_t*)(ws + 32 * MB + 655360);  // 128 KB
  ushort_t* qhi = (ushort_t*)(ws + 33 * MB);       // 2 MB each
  ushort_t* qlo = (ushort_t*)(ws + 35 * MB);
  ushort_t* khi = (ushort_t*)(ws + 37 * MB);
  ushort_t* klo = (ushort_t*)(ws + 39 * MB);
  ushort_t* vv  = (ushort_t*)(ws + 41 * MB);       // 16 MB
  float*    mbuf = (float*)(ws + 57 * MB);         // 128 KB
  float*    lbuf = (float*)(ws + 57 * MB + 131072);// 128 KB
  ushort_t* part0 = xth;   // alias: xt dead after gemm
  ushort_t* part1 = xtl;

  wsplit_kernel<<<dim3(160), dim3(256), 0, stream>>>(Wq, Wk, Wv, wh, wl);
  split_kernel<<<dim3(64, 8, NB), dim3(256), 0, stream>>>(x, xth, xtl);

  const int GSMEM = 65536;
  hipFuncSetAttribute((const void*)gemm_kernel,
                      hipFuncAttributeMaxDynamicSharedMemorySize, GSMEM);
  gemm_kernel<<<dim3(32, 5, NB), dim3(256), GSMEM, stream>>>(
      xth, xtl, wh, wl, bq, bk, bv, qhi, qlo, khi, klo, vv);

  const int ASMEM = 98304;  // 32K K dbuf + 64K V (P scratch eliminated)
  hipFuncSetAttribute((const void*)attn_kernel,
                      hipFuncAttributeMaxDynamicSharedMemorySize, ASMEM);
  attn_kernel<<<dim3(256), dim3(512), ASMEM, stream>>>(
      qhi, qlo, khi, klo, vv, part0, part1, mbuf, lbuf);

  comb_kernel<<<dim3(64, 8, NB), dim3(256), 0, stream>>>(
      part0, part1, mbuf, lbuf, x, gamma, out);
}

// Round 8
// 216.843 us; speedup vs baseline: 1.6721x; 1.0171x over previous
//
#include <hip/hip_runtime.h>
#include <hip/hip_bf16.h>

#define HW 4096
#define NC 512
#define NB 4

typedef float f32x4 __attribute__((ext_vector_type(4)));
typedef float f32x16 __attribute__((ext_vector_type(16)));
typedef short bf16x8 __attribute__((ext_vector_type(8)));
typedef unsigned int u32;
typedef u32 u32x4 __attribute__((ext_vector_type(4)));
typedef unsigned short ushort_t;

#define GLOAD_LDS(g, s) __builtin_amdgcn_global_load_lds((const __attribute__((address_space(1))) void*)(g), (__attribute__((address_space(3))) void*)(s), 16, 0, 0)

__device__ __forceinline__ unsigned short f2bf(float f){
  unsigned int u = __builtin_bit_cast(unsigned int, f);
  u += 0x7FFFu + ((u >> 16) & 1u);
  return (unsigned short)(u >> 16);
}
__device__ __forceinline__ float bf2f(unsigned short h){
  unsigned int u = ((unsigned int)h) << 16;
  return __builtin_bit_cast(float, u);
}

// ---------------- W -> bf16 hi (+lo for q/k rows 0..127) ----------------
__global__ __launch_bounds__(256) void wsplit_kernel(
    const float* __restrict__ Wq, const float* __restrict__ Wk,
    const float* __restrict__ Wv, ushort_t* __restrict__ wh, ushort_t* __restrict__ wl)
{
  long e = ((long)blockIdx.x * 256 + threadIdx.x) * 8;
  int r = (int)(e >> 9), c = (int)(e & 511);
  const float* src = (r < 64)  ? Wq + (long)r * 512 + c
                   : (r < 128) ? Wk + (long)(r - 64) * 512 + c
                               : Wv + (long)(r - 128) * 512 + c;
  f32x4 v0 = *reinterpret_cast<const f32x4*>(src);
  f32x4 v1 = *reinterpret_cast<const f32x4*>(src + 4);
  ushort_t h[8], l[8];
  #pragma unroll
  for (int j = 0; j < 4; j++){ h[j] = f2bf(v0[j]); l[j] = f2bf(v0[j] - bf2f(h[j])); }
  #pragma unroll
  for (int j = 0; j < 4; j++){ h[4+j] = f2bf(v1[j]); l[4+j] = f2bf(v1[j] - bf2f(h[4+j])); }
  *reinterpret_cast<bf16x8*>(wh + e) = *reinterpret_cast<bf16x8*>(h);
  if (r < 128) *reinterpret_cast<bf16x8*>(wl + e) = *reinterpret_cast<bf16x8*>(l);
}

// ---------------- x [b][c][px] fp32 -> xt hi/lo [b][px][c] bf16 ----------------
__global__ __launch_bounds__(256) void split_kernel(
    const float* __restrict__ x, ushort_t* __restrict__ xth, ushort_t* __restrict__ xtl)
{
  const int i0 = blockIdx.x * 64;
  const int c0 = blockIdx.y * 64;
  const int b  = blockIdx.z;
  const int tid = threadIdx.x;
  const int tx = tid & 63, ty = tid >> 6;
  __shared__ float ts[64][65];
  #pragma unroll
  for (int u = 0; u < 16; u++){
    int cl = ty * 16 + u;
    ts[cl][tx] = x[((long)b * NC + c0 + cl) * HW + i0 + tx];
  }
  __syncthreads();
  const int px = tid >> 2;
  const int cs = (tid & 3) * 16;
  ushort_t h[16], l[16];
  #pragma unroll
  for (int e = 0; e < 16; e++){
    float v = ts[cs + e][px];
    h[e] = f2bf(v);
    l[e] = f2bf(v - bf2f(h[e]));
  }
  long base = ((long)b * HW + i0 + px) * 512 + c0 + cs;
  *reinterpret_cast<bf16x8*>(xth + base)     = *reinterpret_cast<bf16x8*>(h);
  *reinterpret_cast<bf16x8*>(xth + base + 8) = *reinterpret_cast<bf16x8*>(h + 8);
  *reinterpret_cast<bf16x8*>(xtl + base)     = *reinterpret_cast<bf16x8*>(l);
  *reinterpret_cast<bf16x8*>(xtl + base + 8) = *reinterpret_cast<bf16x8*>(l + 8);
}

// ---------------- MFMA projection GEMM (unchanged from round 3) ----------------
__global__ __launch_bounds__(256) void gemm_kernel(
    const ushort_t* __restrict__ xth, const ushort_t* __restrict__ xtl,
    const ushort_t* __restrict__ wh, const ushort_t* __restrict__ wl,
    const float* __restrict__ bq, const float* __restrict__ bk, const float* __restrict__ bv,
    ushort_t* __restrict__ qhi, ushort_t* __restrict__ qlo,
    ushort_t* __restrict__ khi, ushort_t* __restrict__ klo,
    ushort_t* __restrict__ vv)
{
  extern __shared__ char lds[];
  const int it = blockIdx.x;
  const int rg = blockIdx.y;
  const int b  = blockIdx.z;
  const int i0 = it * 128;
  const int tid = threadIdx.x;
  const int w = tid >> 6;
  const int lane = tid & 63;
  const int g = lane >> 4, n = lane & 15;
  const int wy = w >> 1, wx = w & 1;

  f32x4 acc[4][4];
  #pragma unroll
  for (int a = 0; a < 4; a++)
    #pragma unroll
    for (int m = 0; m < 4; m++) acc[a][m] = (f32x4){0.f, 0.f, 0.f, 0.f};

  const long xrow = (long)b * HW + i0;

  auto stage = [&](int bsel, int c0s){
    char* dbase = lds + bsel * 32768 + (w << 10);
    #pragma unroll
    for (int u = 0; u < 4; u++){
      int idx = (u << 8) | tid;
      int px = idx >> 3;
      int chs = (idx & 7) ^ (px & 7);
      long go = (xrow + px) * 512 + c0s + chs * 8;
      GLOAD_LDS(xth + go, dbase + (u << 12));
      GLOAD_LDS(xtl + go, dbase + 16384 + (u << 12));
    }
  };

  stage(0, 0);
  asm volatile("s_waitcnt vmcnt(0)" ::: "memory");
  __syncthreads();

  int cur = 0;
  for (int t = 0; t < 8; t++){
    const int c0 = t << 6;
    bf16x8 wfh[4][2], wfl[4][2];
    #pragma unroll
    for (int a = 0; a < 4; a++){
      long R = (long)(rg * 128 + wx * 64 + a * 16 + n) * 512 + c0 + g * 8;
      wfh[a][0] = *reinterpret_cast<const bf16x8*>(wh + R);
      wfh[a][1] = *reinterpret_cast<const bf16x8*>(wh + R + 32);
    }
    if (rg == 0){
      #pragma unroll
      for (int a = 0; a < 4; a++){
        long R = (long)(wx * 64 + a * 16 + n) * 512 + c0 + g * 8;
        wfl[a][0] = *reinterpret_cast<const bf16x8*>(wl + R);
        wfl[a][1] = *reinterpret_cast<const bf16x8*>(wl + R + 32);
      }
    }
    if (t < 7) stage(cur ^ 1, (t + 1) << 6);
    bf16x8 xh[4][2], xl[4][2];
    const char* buf = lds + cur * 32768;
    #pragma unroll
    for (int m = 0; m < 4; m++){
      int px = wy * 64 + m * 16 + n;
      const char* row = buf + px * 128;
      #pragma unroll
      for (int ks = 0; ks < 2; ks++){
        int off = (((ks << 2) | g) ^ (px & 7)) << 4;
        xh[m][ks] = *reinterpret_cast<const bf16x8*>(row + off);
        xl[m][ks] = *reinterpret_cast<const bf16x8*>(row + 16384 + off);
      }
    }
    __builtin_amdgcn_s_setprio(1);
    if (rg == 0){
      #pragma unroll
      for (int a = 0; a < 4; a++)
        #pragma unroll
        for (int m = 0; m < 4; m++)
          #pragma unroll
          for (int ks = 0; ks < 2; ks++){
            acc[a][m] = __builtin_amdgcn_mfma_f32_16x16x32_bf16(xh[m][ks], wfh[a][ks], acc[a][m], 0, 0, 0);
            acc[a][m] = __builtin_amdgcn_mfma_f32_16x16x32_bf16(xl[m][ks], wfh[a][ks], acc[a][m], 0, 0, 0);
            acc[a][m] = __builtin_amdgcn_mfma_f32_16x16x32_bf16(xh[m][ks], wfl[a][ks], acc[a][m], 0, 0, 0);
          }
    } else {
      #pragma unroll
      for (int a = 0; a < 4; a++)
        #pragma unroll
        for (int m = 0; m < 4; m++)
          #pragma unroll
          for (int ks = 0; ks < 2; ks++){
            acc[a][m] = __builtin_amdgcn_mfma_f32_16x16x32_bf16(wfh[a][ks], xh[m][ks], acc[a][m], 0, 0, 0);
            acc[a][m] = __builtin_amdgcn_mfma_f32_16x16x32_bf16(wfh[a][ks], xl[m][ks], acc[a][m], 0, 0, 0);
          }
    }
    __builtin_amdgcn_s_setprio(0);
    asm volatile("s_waitcnt vmcnt(0)" ::: "memory");
    __syncthreads();
    cur ^= 1;
  }

  if (rg == 0){
    ushort_t* hs = wx ? khi : qhi;
    ushort_t* ls = wx ? klo : qlo;
    const float* bias = wx ? bk : bq;
    #pragma unroll
    for (int a = 0; a < 4; a++){
      float bb = bias[a * 16 + n];
      #pragma unroll
      for (int m = 0; m < 4; m++){
        #pragma unroll
        for (int r4 = 0; r4 < 4; r4++){
          int px = wy * 64 + m * 16 + g * 4 + r4;
          float v = acc[a][m][r4] + bb;
          ushort_t h = f2bf(v);
          ushort_t l = f2bf(v - bf2f(h));
          long ad = (xrow + px) * 64 + a * 16 + n;
          hs[ad] = h;
          ls[ad] = l;
        }
      }
    }
  } else {
    #pragma unroll
    for (int a = 0; a < 4; a++){
      #pragma unroll
      for (int r4 = 0; r4 < 4; r4++){
        int C = (rg - 1) * 128 + wx * 64 + a * 16 + g * 4 + r4;
        float bb = bv[C];
        #pragma unroll
        for (int m = 0; m < 4; m++){
          int px = wy * 64 + m * 16 + n;
          vv[((long)b * NC + C) * HW + i0 + px] = f2bf(acc[a][m][r4] + bb);
        }
      }
    }
  }
}

// ---------------- flash attention: swapped-QK 32x32, full K+V double-buffer ----------------
// 1D grid 256; decode: xcd = wgid&7 -> (jh = xcd>>2, b = xcd&3), qt = wgid>>3.
// Block 512 thr (8 waves): wave w -> rg = w>>1 (32 q rows), ch = w&1 (256-c half).
// Per lane: q = i0w + (lane&31). 32 iters over 64-j subtiles.
// Pipeline: [stage K/V (t+1) -> ~cur] QK(cur) -> softmax/pack (permlane32_swap)
//           -> PV(cur) -> vmcnt(0) (own stores landed an iter ago) -> ONE barrier.
// LDS 160K: [0,16K) K buf0 | [16K,32K) K buf1 | [32K,96K) V buf0 | [96K,160K) V buf1
__global__ __launch_bounds__(512, 1) void attn_kernel(
    const ushort_t* __restrict__ qhi, const ushort_t* __restrict__ qlo,
    const ushort_t* __restrict__ khi, const ushort_t* __restrict__ klo,
    const ushort_t* __restrict__ vv,
    ushort_t* __restrict__ p0, ushort_t* __restrict__ p1,
    float* __restrict__ mbuf, float* __restrict__ lbuf)
{
  extern __shared__ char smem[];
  const int wgid = blockIdx.x;
  const int xcd = wgid & 7;
  const int jh = xcd >> 2;
  const int b  = xcd & 3;
  const int qt = wgid >> 3;
  const int tid = threadIdx.x;
  const int w = tid >> 6;
  const int lane = tid & 63;
  const int q32 = lane & 31;
  const int hh = lane >> 5;
  const int rg = w >> 1, ch = w & 1;
  const int i0w = qt * 128 + rg * 32;
  const int c0w = ch * 256;
  const int jbase = jh * 2048;

  const int kj = tid >> 3;
  const int kdblk = (tid & 7) ^ (kj & 7);
  const long kgbase = ((long)b * HW + kj) * 64 + kdblk * 8;

  auto stageK = [&](int bsel, int j0){
    char* dst = smem + bsel * 16384 + (w << 10);
    GLOAD_LDS(khi + kgbase + (long)j0 * 64, dst);
    GLOAD_LDS(klo + kgbase + (long)j0 * 64, dst + 8192);
  };
  auto stageV = [&](int bsel, int j0){
    char* dbase = smem + 32768 + bsel * 65536 + (w << 10);
    #pragma unroll
    for (int r = 0; r < 8; r++){
      int ss = (r << 9) | tid;
      int c = ss >> 3;
      int jblk = (ss & 7) ^ (c & 7);
      long goff = (long)b * (NC * HW) + (long)c * HW + j0 + jblk * 8;
      GLOAD_LDS(vv + goff, dbase + (r << 13));
    }
  };

  // Q fragments (B-operand): col q = lane&31, k(d) = chain*16 + hh*8 + e
  bf16x8 aqh[4], aql[4];
  #pragma unroll
  for (int c = 0; c < 4; c++){
    long qb = ((long)b * HW + i0w + q32) * 64 + c * 16 + hh * 8;
    aqh[c] = *reinterpret_cast<const bf16x8*>(qhi + qb);
    aql[c] = *reinterpret_cast<const bf16x8*>(qlo + qb);
  }

  f32x16 acc[8];
  #pragma unroll
  for (int ct = 0; ct < 8; ct++)
    #pragma unroll
    for (int r = 0; r < 16; r++) acc[ct][r] = 0.f;
  float mrow = -1e30f, lrow = 0.f;

  stageK(0, jbase);
  stageV(0, jbase);
  asm volatile("s_waitcnt vmcnt(0)" ::: "memory");
  __syncthreads();

  int cur = 0;
  for (int t = 0; t < 32; t++){
    // 1. prefetch next K+V subtile into ~cur (10 loads; whole iteration to land)
    if (t < 31){
      stageK(cur ^ 1, jbase + (t + 1) * 64);
      stageV(cur ^ 1, jbase + (t + 1) * 64);
    }
    // 2. QK swapped: S[j, q] (3-term hi/lo), two 32-j tiles
    f32x16 sv[2];
    {
      const char* kb0 = smem + cur * 16384;
      __builtin_amdgcn_s_setprio(1);
      #pragma unroll
      for (int jt = 0; jt < 2; jt++){
        int jrow = jt * 32 + q32;
        const char* krow = kb0 + jrow * 128;
        int r7 = jrow & 7;
        f32x16 s;
        #pragma unroll
        for (int r = 0; r < 16; r++) s[r] = 0.f;
        #pragma unroll
        for (int c = 0; c < 4; c++){
          int off = (((c << 1) | hh) ^ r7) << 4;
          bf16x8 kh = *(const bf16x8*)(krow + off);
          bf16x8 kl = *(const bf16x8*)(krow + 8192 + off);
          s = __builtin_amdgcn_mfma_f32_32x32x16_bf16(kh, aqh[c], s, 0, 0, 0);
          s = __builtin_amdgcn_mfma_f32_32x32x16_bf16(kh, aql[c], s, 0, 0, 0);
          s = __builtin_amdgcn_mfma_f32_32x32x16_bf16(kl, aqh[c], s, 0, 0, 0);
        }
        sv[jt] = s;
      }
      __builtin_amdgcn_s_setprio(0);
    }
    // 3. in-lane softmax with defer-max (T13)
    {
      f32x16 mx;
      #pragma unroll
      for (int r = 0; r < 16; r++) mx[r] = fmaxf(sv[0][r], sv[1][r]);
      float m8[8];
      #pragma unroll
      for (int r = 0; r < 8; r++) m8[r] = fmaxf(mx[r], mx[r + 8]);
      float m4a = fmaxf(m8[0], m8[4]), m4b = fmaxf(m8[1], m8[5]);
      float m4c = fmaxf(m8[2], m8[6]), m4d = fmaxf(m8[3], m8[7]);
      float tmx = fmaxf(fmaxf(m4a, m4b), fmaxf(m4c, m4d));
      tmx = fmaxf(tmx, __shfl_xor(tmx, 32));
      if (__any(tmx > mrow + 8.f)){
        float mnew = fmaxf(mrow, tmx);
        float sc = __expf(mrow - mnew);
        lrow *= sc;
        #pragma unroll
        for (int ct = 0; ct < 8; ct++)
          #pragma unroll
          for (int r = 0; r < 16; r++) acc[ct][r] *= sc;
        mrow = mnew;
      }
    }
    // 4. P = exp(S - m), row-sum, pack to MFMA frags via permlane32_swap
    bf16x8 pa[4];
    {
      #pragma unroll
      for (int jt = 0; jt < 2; jt++)
        #pragma unroll
        for (int r = 0; r < 16; r++) sv[jt][r] = __expf(sv[jt][r] - mrow);
      float rs = 0.f;
      #pragma unroll
      for (int r = 0; r < 16; r++) rs += sv[0][r] + sv[1][r];
      rs += __shfl_xor(rs, 32);
      lrow += rs;
      #pragma unroll
      for (int jt = 0; jt < 2; jt++){
        u32 pk[8];
        #pragma unroll
        for (int i = 0; i < 8; i++){
          float a = sv[jt][2 * i], bb = sv[jt][2 * i + 1];
          u32 d;
          asm("v_cvt_pk_bf16_f32 %0, %1, %2" : "=v"(d) : "v"(a), "v"(bb));
          pk[i] = d;
        }
        #pragma unroll
        for (int cc = 0; cc < 2; cc++){
          u32 a0 = pk[4 * cc + 0], b0 = pk[4 * cc + 2];
          u32 a1 = pk[4 * cc + 1], b1 = pk[4 * cc + 3];
          // swap hi(a) <-> lo(b): gives both halves' needed words, no selects
          asm volatile("v_permlane32_swap_b32 %0, %1" : "+v"(a0), "+v"(b0));
          asm volatile("v_permlane32_swap_b32 %0, %1" : "+v"(a1), "+v"(b1));
          u32x4 wv;
          wv[0] = a0; wv[1] = a1; wv[2] = b0; wv[3] = b1;
          pa[jt * 2 + cc] = __builtin_bit_cast(bf16x8, wv);
        }
      }
    }
    // 5. PV on V[cur] (published at the previous barrier; no mid-iter wait)
    {
      const char* vb = smem + 32768 + cur * 65536;
      __builtin_amdgcn_s_setprio(1);
      #pragma unroll
      for (int ct = 0; ct < 8; ct++){
        int row = c0w + ct * 32 + q32;
        const char* vrow = vb + row * 128;
        int r7 = row & 7;
        #pragma unroll
        for (int c = 0; c < 4; c++){
          int off = (((c << 1) | hh) ^ r7) << 4;
          bf16x8 vf = *(const bf16x8*)(vrow + off);
          acc[ct] = __builtin_amdgcn_mfma_f32_32x32x16_bf16(vf, pa[c], acc[ct], 0, 0, 0);
        }
      }
      __builtin_amdgcn_s_setprio(0);
    }
    // 6. publish next buffers: own staging landed (issued a full iter ago), sync
    asm volatile("s_waitcnt vmcnt(0)" ::: "memory");
    __syncthreads();
    cur ^= 1;
  }

  // epilogue: unnormalized partial bf16, [b][c][i] layout (coalesced in i)
  ushort_t* pd = jh ? p1 : p0;
  const int i = i0w + q32;
  #pragma unroll
  for (int ct = 0; ct < 8; ct++){
    #pragma unroll
    for (int r = 0; r < 16; r++){
      int c = c0w + ct * 32 + (r & 3) + 8 * (r >> 2) + 4 * hh;
      pd[((long)b * NC + c) * HW + i] = f2bf(acc[ct][r]);
    }
  }
  if (ch == 0 && lane < 32){
    int gi = b * HW + i0w + lane;
    mbuf[jh * (NB * HW) + gi] = mrow;
    lbuf[jh * (NB * HW) + gi] = lrow;
  }
}

// ---------------- combine halves + epilogue: out = gamma * O + x ----------------
__global__ __launch_bounds__(256) void comb_kernel(
    const ushort_t* __restrict__ p0, const ushort_t* __restrict__ p1,
    const float* __restrict__ mbuf, const float* __restrict__ lbuf,
    const float* __restrict__ x, const float* __restrict__ gamma,
    float* __restrict__ out)
{
  const int it = blockIdx.x;
  const int ct = blockIdx.y;
  const int b  = blockIdx.z;
  const int i0 = it * 64, c0 = ct * 64;
  const int tid = threadIdx.x;
  const int tx = tid & 63, ty = tid >> 6;
  __shared__ float f0s[64], f1s[64];
  const float gm = gamma[0];
  if (tid < 64){
    int gi = b * HW + i0 + tid;
    float m0 = mbuf[gi], m1 = mbuf[NB * HW + gi];
    float l0 = lbuf[gi], l1 = lbuf[NB * HW + gi];
    float M = fmaxf(m0, m1);
    float w0 = __expf(m0 - M), w1 = __expf(m1 - M);
    float rden = 1.f / (w0 * l0 + w1 * l1);
    f0s[tid] = w0 * rden;
    f1s[tid] = w1 * rden;
  }
  __syncthreads();
  #pragma unroll
  for (int u = 0; u < 16; u++){
    int cl = ty * 16 + u;
    long idx = ((long)b * NC + c0 + cl) * HW + i0 + tx;
    float o = f0s[tx] * bf2f(p0[idx]) + f1s[tx] * bf2f(p1[idx]);
    out[idx] = fmaf(gm, o, x[idx]);
  }
}

extern "C" void kernel_launch(void* const* d_in, const int* in_sizes, int n_in,
                              void* d_out, int out_size, void* d_ws, size_t ws_size,
                              hipStream_t stream)
{
  const float* x  = (const float*)d_in[0];
  const float* Wq = (const float*)d_in[1];
  const float* bq = (const float*)d_in[2];
  const float* Wk = (const float*)d_in[3];
  const float* bk = (const float*)d_in[4];
  const float* Wv = (const float*)d_in[5];
  const float* bv = (const float*)d_in[6];
  const float* gamma = (const float*)d_in[7];
  float* out = (float*)d_out;

  char* ws = (char*)d_ws;
  const size_t MB = 1024 * 1024;
  ushort_t* xth = (ushort_t*)(ws);                 // 16 MB, reused as partial0
  ushort_t* xtl = (ushort_t*)(ws + 16 * MB);       // 16 MB, reused as partial1
  ushort_t* wh  = (ushort_t*)(ws + 32 * MB);       // 640 KB
  ushort_t* wl  = (ushort_t*)(ws + 32 * MB + 655360);  // 128 KB
  ushort_t* qhi = (ushort_t*)(ws + 33 * MB);       // 2 MB each
  ushort_t* qlo = (ushort_t*)(ws + 35 * MB);
  ushort_t* khi = (ushort_t*)(ws + 37 * MB);
  ushort_t* klo = (ushort_t*)(ws + 39 * MB);
  ushort_t* vv  = (ushort_t*)(ws + 41 * MB);       // 16 MB
  float*    mbuf = (float*)(ws + 57 * MB);         // 128 KB
  float*    lbuf = (float*)(ws + 57 * MB + 131072);// 128 KB
  ushort_t* part0 = xth;   // alias: xt dead after gemm
  ushort_t* part1 = xtl;

  wsplit_kernel<<<dim3(160), dim3(256), 0, stream>>>(Wq, Wk, Wv, wh, wl);
  split_kernel<<<dim3(64, 8, NB), dim3(256), 0, stream>>>(x, xth, xtl);

  const int GSMEM = 65536;
  hipFuncSetAttribute((const void*)gemm_kernel,
                      hipFuncAttributeMaxDynamicSharedMemorySize, GSMEM);
  gemm_kernel<<<dim3(32, 5, NB), dim3(256), GSMEM, stream>>>(
      xth, xtl, wh, wl, bq, bk, bv, qhi, qlo, khi, klo, vv);

  const int ASMEM = 163840;  // 32K K dbuf + 128K V dbuf (full CU LDS)
  hipFuncSetAttribute((const void*)attn_kernel,
                      hipFuncAttributeMaxDynamicSharedMemorySize, ASMEM);
  attn_kernel<<<dim3(256), dim3(512), ASMEM, stream>>>(
      qhi, qlo, khi, klo, vv, part0, part1, mbuf, lbuf);

  comb_kernel<<<dim3(64, 8, NB), dim3(256), 0, stream>>>(
      part0, part1, mbuf, lbuf, x, gamma, out);
}

// Round 9
// 212.015 us; speedup vs baseline: 1.7102x; 1.0228x over previous
//
#include <hip/hip_runtime.h>
#include <hip/hip_bf16.h>
#include <math.h>

#define HW 4096
#define NC 512
#define NB 4

typedef float f32x4 __attribute__((ext_vector_type(4)));
typedef float f32x16 __attribute__((ext_vector_type(16)));
typedef short bf16x8 __attribute__((ext_vector_type(8)));
typedef unsigned int u32;
typedef u32 u32x4 __attribute__((ext_vector_type(4)));
typedef unsigned short ushort_t;

#define GLOAD_LDS(g, s) __builtin_amdgcn_global_load_lds((const __attribute__((address_space(1))) void*)(g), (__attribute__((address_space(3))) void*)(s), 16, 0, 0)

__device__ __forceinline__ unsigned short f2bf(float f){
  unsigned int u = __builtin_bit_cast(unsigned int, f);
  u += 0x7FFFu + ((u >> 16) & 1u);
  return (unsigned short)(u >> 16);
}
__device__ __forceinline__ float bf2f(unsigned short h){
  unsigned int u = ((unsigned int)h) << 16;
  return __builtin_bit_cast(float, u);
}

// ---------------- W -> bf16 hi (+lo for q/k rows 0..127) ----------------
__global__ __launch_bounds__(256) void wsplit_kernel(
    const float* __restrict__ Wq, const float* __restrict__ Wk,
    const float* __restrict__ Wv, ushort_t* __restrict__ wh, ushort_t* __restrict__ wl)
{
  long e = ((long)blockIdx.x * 256 + threadIdx.x) * 8;
  int r = (int)(e >> 9), c = (int)(e & 511);
  const float* src = (r < 64)  ? Wq + (long)r * 512 + c
                   : (r < 128) ? Wk + (long)(r - 64) * 512 + c
                               : Wv + (long)(r - 128) * 512 + c;
  f32x4 v0 = *reinterpret_cast<const f32x4*>(src);
  f32x4 v1 = *reinterpret_cast<const f32x4*>(src + 4);
  ushort_t h[8], l[8];
  #pragma unroll
  for (int j = 0; j < 4; j++){ h[j] = f2bf(v0[j]); l[j] = f2bf(v0[j] - bf2f(h[j])); }
  #pragma unroll
  for (int j = 0; j < 4; j++){ h[4+j] = f2bf(v1[j]); l[4+j] = f2bf(v1[j] - bf2f(h[4+j])); }
  *reinterpret_cast<bf16x8*>(wh + e) = *reinterpret_cast<bf16x8*>(h);
  if (r < 128) *reinterpret_cast<bf16x8*>(wl + e) = *reinterpret_cast<bf16x8*>(l);
}

// ---------------- x [b][c][px] fp32 -> xt hi/lo [b][px][c] bf16 ----------------
__global__ __launch_bounds__(256) void split_kernel(
    const float* __restrict__ x, ushort_t* __restrict__ xth, ushort_t* __restrict__ xtl)
{
  const int i0 = blockIdx.x * 64;
  const int c0 = blockIdx.y * 64;
  const int b  = blockIdx.z;
  const int tid = threadIdx.x;
  const int tx = tid & 63, ty = tid >> 6;
  __shared__ float ts[64][65];
  #pragma unroll
  for (int u = 0; u < 16; u++){
    int cl = ty * 16 + u;
    ts[cl][tx] = x[((long)b * NC + c0 + cl) * HW + i0 + tx];
  }
  __syncthreads();
  const int px = tid >> 2;
  const int cs = (tid & 3) * 16;
  ushort_t h[16], l[16];
  #pragma unroll
  for (int e = 0; e < 16; e++){
    float v = ts[cs + e][px];
    h[e] = f2bf(v);
    l[e] = f2bf(v - bf2f(h[e]));
  }
  long base = ((long)b * HW + i0 + px) * 512 + c0 + cs;
  *reinterpret_cast<bf16x8*>(xth + base)     = *reinterpret_cast<bf16x8*>(h);
  *reinterpret_cast<bf16x8*>(xth + base + 8) = *reinterpret_cast<bf16x8*>(h + 8);
  *reinterpret_cast<bf16x8*>(xtl + base)     = *reinterpret_cast<bf16x8*>(l);
  *reinterpret_cast<bf16x8*>(xtl + base + 8) = *reinterpret_cast<bf16x8*>(l + 8);
}

// ---------------- MFMA projection GEMM ----------------
// q rows are pre-scaled by log2(e) so attention can use exp2 directly.
__global__ __launch_bounds__(256) void gemm_kernel(
    const ushort_t* __restrict__ xth, const ushort_t* __restrict__ xtl,
    const ushort_t* __restrict__ wh, const ushort_t* __restrict__ wl,
    const float* __restrict__ bq, const float* __restrict__ bk, const float* __restrict__ bv,
    ushort_t* __restrict__ qhi, ushort_t* __restrict__ qlo,
    ushort_t* __restrict__ khi, ushort_t* __restrict__ klo,
    ushort_t* __restrict__ vv)
{
  extern __shared__ char lds[];
  const int it = blockIdx.x;
  const int rg = blockIdx.y;
  const int b  = blockIdx.z;
  const int i0 = it * 128;
  const int tid = threadIdx.x;
  const int w = tid >> 6;
  const int lane = tid & 63;
  const int g = lane >> 4, n = lane & 15;
  const int wy = w >> 1, wx = w & 1;

  f32x4 acc[4][4];
  #pragma unroll
  for (int a = 0; a < 4; a++)
    #pragma unroll
    for (int m = 0; m < 4; m++) acc[a][m] = (f32x4){0.f, 0.f, 0.f, 0.f};

  const long xrow = (long)b * HW + i0;

  auto stage = [&](int bsel, int c0s){
    char* dbase = lds + bsel * 32768 + (w << 10);
    #pragma unroll
    for (int u = 0; u < 4; u++){
      int idx = (u << 8) | tid;
      int px = idx >> 3;
      int chs = (idx & 7) ^ (px & 7);
      long go = (xrow + px) * 512 + c0s + chs * 8;
      GLOAD_LDS(xth + go, dbase + (u << 12));
      GLOAD_LDS(xtl + go, dbase + 16384 + (u << 12));
    }
  };

  stage(0, 0);
  asm volatile("s_waitcnt vmcnt(0)" ::: "memory");
  __syncthreads();

  int cur = 0;
  for (int t = 0; t < 8; t++){
    const int c0 = t << 6;
    bf16x8 wfh[4][2], wfl[4][2];
    #pragma unroll
    for (int a = 0; a < 4; a++){
      long R = (long)(rg * 128 + wx * 64 + a * 16 + n) * 512 + c0 + g * 8;
      wfh[a][0] = *reinterpret_cast<const bf16x8*>(wh + R);
      wfh[a][1] = *reinterpret_cast<const bf16x8*>(wh + R + 32);
    }
    if (rg == 0){
      #pragma unroll
      for (int a = 0; a < 4; a++){
        long R = (long)(wx * 64 + a * 16 + n) * 512 + c0 + g * 8;
        wfl[a][0] = *reinterpret_cast<const bf16x8*>(wl + R);
        wfl[a][1] = *reinterpret_cast<const bf16x8*>(wl + R + 32);
      }
    }
    if (t < 7) stage(cur ^ 1, (t + 1) << 6);
    bf16x8 xh[4][2], xl[4][2];
    const char* buf = lds + cur * 32768;
    #pragma unroll
    for (int m = 0; m < 4; m++){
      int px = wy * 64 + m * 16 + n;
      const char* row = buf + px * 128;
      #pragma unroll
      for (int ks = 0; ks < 2; ks++){
        int off = (((ks << 2) | g) ^ (px & 7)) << 4;
        xh[m][ks] = *reinterpret_cast<const bf16x8*>(row + off);
        xl[m][ks] = *reinterpret_cast<const bf16x8*>(row + 16384 + off);
      }
    }
    __builtin_amdgcn_s_setprio(1);
    if (rg == 0){
      #pragma unroll
      for (int a = 0; a < 4; a++)
        #pragma unroll
        for (int m = 0; m < 4; m++)
          #pragma unroll
          for (int ks = 0; ks < 2; ks++){
            acc[a][m] = __builtin_amdgcn_mfma_f32_16x16x32_bf16(xh[m][ks], wfh[a][ks], acc[a][m], 0, 0, 0);
            acc[a][m] = __builtin_amdgcn_mfma_f32_16x16x32_bf16(xl[m][ks], wfh[a][ks], acc[a][m], 0, 0, 0);
            acc[a][m] = __builtin_amdgcn_mfma_f32_16x16x32_bf16(xh[m][ks], wfl[a][ks], acc[a][m], 0, 0, 0);
          }
    } else {
      #pragma unroll
      for (int a = 0; a < 4; a++)
        #pragma unroll
        for (int m = 0; m < 4; m++)
          #pragma unroll
          for (int ks = 0; ks < 2; ks++){
            acc[a][m] = __builtin_amdgcn_mfma_f32_16x16x32_bf16(wfh[a][ks], xh[m][ks], acc[a][m], 0, 0, 0);
            acc[a][m] = __builtin_amdgcn_mfma_f32_16x16x32_bf16(wfh[a][ks], xl[m][ks], acc[a][m], 0, 0, 0);
          }
    }
    __builtin_amdgcn_s_setprio(0);
    asm volatile("s_waitcnt vmcnt(0)" ::: "memory");
    __syncthreads();
    cur ^= 1;
  }

  if (rg == 0){
    ushort_t* hs = wx ? khi : qhi;
    ushort_t* ls = wx ? klo : qlo;
    const float* bias = wx ? bk : bq;
    const float qscale = wx ? 1.0f : 1.44269504088896f;  // q in log2 domain
    #pragma unroll
    for (int a = 0; a < 4; a++){
      float bb = bias[a * 16 + n];
      #pragma unroll
      for (int m = 0; m < 4; m++){
        #pragma unroll
        for (int r4 = 0; r4 < 4; r4++){
          int px = wy * 64 + m * 16 + g * 4 + r4;
          float v = (acc[a][m][r4] + bb) * qscale;
          ushort_t h = f2bf(v);
          ushort_t l = f2bf(v - bf2f(h));
          long ad = (xrow + px) * 64 + a * 16 + n;
          hs[ad] = h;
          ls[ad] = l;
        }
      }
    }
  } else {
    #pragma unroll
    for (int a = 0; a < 4; a++){
      #pragma unroll
      for (int r4 = 0; r4 < 4; r4++){
        int C = (rg - 1) * 128 + wx * 64 + a * 16 + g * 4 + r4;
        float bb = bv[C];
        #pragma unroll
        for (int m = 0; m < 4; m++){
          int px = wy * 64 + m * 16 + n;
          vv[((long)b * NC + C) * HW + i0 + px] = f2bf(acc[a][m][r4] + bb);
        }
      }
    }
  }
}

// ---------------- flash attention: swapped-QK 32x32, 2-term QK, exp2 softmax ----------------
// 1D grid 256; decode: xcd = wgid&7 -> (jh = xcd>>2, b = xcd&3), qt = wgid>>3.
// Block 512 thr (8 waves): wave w -> rg = w>>1 (32 q rows), ch = w&1 (256-c half).
// Per lane: q = i0w + (lane&31). 32 iters over 64-j subtiles.
// S = kh·(qh + ql) (2-term; dropped qh·kl term ~1.2e-2 logit noise).
// LDS 144K: [0,8K) K buf0 | [8K,16K) K buf1 | [16K,80K) V buf0 | [80K,144K) V buf1
__global__ __launch_bounds__(512, 1) void attn_kernel(
    const ushort_t* __restrict__ qhi, const ushort_t* __restrict__ qlo,
    const ushort_t* __restrict__ khi,
    const ushort_t* __restrict__ vv,
    ushort_t* __restrict__ p0, ushort_t* __restrict__ p1,
    float* __restrict__ mbuf, float* __restrict__ lbuf)
{
  extern __shared__ char smem[];
  const int wgid = blockIdx.x;
  const int xcd = wgid & 7;
  const int jh = xcd >> 2;
  const int b  = xcd & 3;
  const int qt = wgid >> 3;
  const int tid = threadIdx.x;
  const int w = tid >> 6;
  const int lane = tid & 63;
  const int q32 = lane & 31;
  const int hh = lane >> 5;
  const int rg = w >> 1, ch = w & 1;
  const int i0w = qt * 128 + rg * 32;
  const int c0w = ch * 256;
  const int jbase = jh * 2048;

  const int kj = tid >> 3;
  const int kdblk = (tid & 7) ^ (kj & 7);
  const long kgbase = ((long)b * HW + kj) * 64 + kdblk * 8;

  auto stageK = [&](int bsel, int j0){
    char* dst = smem + bsel * 8192 + (tid >> 6 << 10);
    GLOAD_LDS(khi + kgbase + (long)j0 * 64, dst);
  };
  auto stageV = [&](int bsel, int j0){
    char* dbase = smem + 16384 + bsel * 65536 + (w << 10);
    #pragma unroll
    for (int r = 0; r < 8; r++){
      int ss = (r << 9) | tid;
      int c = ss >> 3;
      int jblk = (ss & 7) ^ (c & 7);
      long goff = (long)b * (NC * HW) + (long)c * HW + j0 + jblk * 8;
      GLOAD_LDS(vv + goff, dbase + (r << 13));
    }
  };

  // Q fragments (B-operand): col q = lane&31, k(d) = chain*16 + hh*8 + e
  bf16x8 aqh[4], aql[4];
  #pragma unroll
  for (int c = 0; c < 4; c++){
    long qb = ((long)b * HW + i0w + q32) * 64 + c * 16 + hh * 8;
    aqh[c] = *reinterpret_cast<const bf16x8*>(qhi + qb);
    aql[c] = *reinterpret_cast<const bf16x8*>(qlo + qb);
  }

  f32x16 acc[8];
  #pragma unroll
  for (int ct = 0; ct < 8; ct++)
    #pragma unroll
    for (int r = 0; r < 16; r++) acc[ct][r] = 0.f;
  float mrow = -1e30f, lrow = 0.f;

  stageK(0, jbase);
  stageV(0, jbase);
  asm volatile("s_waitcnt vmcnt(0)" ::: "memory");
  __syncthreads();

  int cur = 0;
  for (int t = 0; t < 32; t++){
    // 1. prefetch next K+V subtile into ~cur (9 loads; whole iteration to land)
    if (t < 31){
      stageK(cur ^ 1, jbase + (t + 1) * 64);
      stageV(cur ^ 1, jbase + (t + 1) * 64);
    }
    // 2. QK swapped: S[j, q] = kh·(qh + ql), log2 domain
    f32x16 sv[2];
    {
      const char* kb0 = smem + cur * 8192;
      __builtin_amdgcn_s_setprio(1);
      #pragma unroll
      for (int jt = 0; jt < 2; jt++){
        int jrow = jt * 32 + q32;
        const char* krow = kb0 + jrow * 128;
        int r7 = jrow & 7;
        f32x16 s;
        #pragma unroll
        for (int r = 0; r < 16; r++) s[r] = 0.f;
        #pragma unroll
        for (int c = 0; c < 4; c++){
          int off = (((c << 1) | hh) ^ r7) << 4;
          bf16x8 kh = *(const bf16x8*)(krow + off);
          s = __builtin_amdgcn_mfma_f32_32x32x16_bf16(kh, aqh[c], s, 0, 0, 0);
          s = __builtin_amdgcn_mfma_f32_32x32x16_bf16(kh, aql[c], s, 0, 0, 0);
        }
        sv[jt] = s;
      }
      __builtin_amdgcn_s_setprio(0);
    }
    // 3. in-lane softmax with defer-max (T13, log2 units: 8 nats ~= 11.5)
    {
      f32x16 mx;
      #pragma unroll
      for (int r = 0; r < 16; r++) mx[r] = fmaxf(sv[0][r], sv[1][r]);
      float m8[8];
      #pragma unroll
      for (int r = 0; r < 8; r++) m8[r] = fmaxf(mx[r], mx[r + 8]);
      float m4a = fmaxf(m8[0], m8[4]), m4b = fmaxf(m8[1], m8[5]);
      float m4c = fmaxf(m8[2], m8[6]), m4d = fmaxf(m8[3], m8[7]);
      float tmx = fmaxf(fmaxf(m4a, m4b), fmaxf(m4c, m4d));
      tmx = fmaxf(tmx, __shfl_xor(tmx, 32));
      if (__any(tmx > mrow + 11.5f)){
        float mnew = fmaxf(mrow, tmx);
        float sc = exp2f(mrow - mnew);
        lrow *= sc;
        #pragma unroll
        for (int ct = 0; ct < 8; ct++)
          #pragma unroll
          for (int r = 0; r < 16; r++) acc[ct][r] *= sc;
        mrow = mnew;
      }
    }
    // 4. P = exp2(S - m), row-sum, pack to MFMA frags via permlane32_swap
    bf16x8 pa[4];
    {
      #pragma unroll
      for (int jt = 0; jt < 2; jt++)
        #pragma unroll
        for (int r = 0; r < 16; r++) sv[jt][r] = exp2f(sv[jt][r] - mrow);
      float rs = 0.f;
      #pragma unroll
      for (int r = 0; r < 16; r++) rs += sv[0][r] + sv[1][r];
      rs += __shfl_xor(rs, 32);
      lrow += rs;
      #pragma unroll
      for (int jt = 0; jt < 2; jt++){
        u32 pk[8];
        #pragma unroll
        for (int i = 0; i < 8; i++){
          float a = sv[jt][2 * i], bb = sv[jt][2 * i + 1];
          u32 d;
          asm("v_cvt_pk_bf16_f32 %0, %1, %2" : "=v"(d) : "v"(a), "v"(bb));
          pk[i] = d;
        }
        #pragma unroll
        for (int cc = 0; cc < 2; cc++){
          u32 a0 = pk[4 * cc + 0], b0 = pk[4 * cc + 2];
          u32 a1 = pk[4 * cc + 1], b1 = pk[4 * cc + 3];
          asm volatile("v_permlane32_swap_b32 %0, %1" : "+v"(a0), "+v"(b0));
          asm volatile("v_permlane32_swap_b32 %0, %1" : "+v"(a1), "+v"(b1));
          u32x4 wv;
          wv[0] = a0; wv[1] = a1; wv[2] = b0; wv[3] = b1;
          pa[jt * 2 + cc] = __builtin_bit_cast(bf16x8, wv);
        }
      }
    }
    // 5. PV on V[cur]
    {
      const char* vb = smem + 16384 + cur * 65536;
      __builtin_amdgcn_s_setprio(1);
      #pragma unroll
      for (int ct = 0; ct < 8; ct++){
        int row = c0w + ct * 32 + q32;
        const char* vrow = vb + row * 128;
        int r7 = row & 7;
        #pragma unroll
        for (int c = 0; c < 4; c++){
          int off = (((c << 1) | hh) ^ r7) << 4;
          bf16x8 vf = *(const bf16x8*)(vrow + off);
          acc[ct] = __builtin_amdgcn_mfma_f32_32x32x16_bf16(vf, pa[c], acc[ct], 0, 0, 0);
        }
      }
      __builtin_amdgcn_s_setprio(0);
    }
    // 6. publish next buffers: own staging landed, sync
    asm volatile("s_waitcnt vmcnt(0)" ::: "memory");
    __syncthreads();
    cur ^= 1;
  }

  // epilogue: unnormalized partial bf16, [b][c][i] layout (coalesced in i)
  ushort_t* pd = jh ? p1 : p0;
  const int i = i0w + q32;
  #pragma unroll
  for (int ct = 0; ct < 8; ct++){
    #pragma unroll
    for (int r = 0; r < 16; r++){
      int c = c0w + ct * 32 + (r & 3) + 8 * (r >> 2) + 4 * hh;
      pd[((long)b * NC + c) * HW + i] = f2bf(acc[ct][r]);
    }
  }
  if (ch == 0 && lane < 32){
    int gi = b * HW + i0w + lane;
    mbuf[jh * (NB * HW) + gi] = mrow;
    lbuf[jh * (NB * HW) + gi] = lrow;
  }
}

// ---------------- combine halves + epilogue: out = gamma * O + x ----------------
__global__ __launch_bounds__(256) void comb_kernel(
    const ushort_t* __restrict__ p0, const ushort_t* __restrict__ p1,
    const float* __restrict__ mbuf, const float* __restrict__ lbuf,
    const float* __restrict__ x, const float* __restrict__ gamma,
    float* __restrict__ out)
{
  const int it = blockIdx.x;
  const int ct = blockIdx.y;
  const int b  = blockIdx.z;
  const int i0 = it * 64, c0 = ct * 64;
  const int tid = threadIdx.x;
  const int tx = tid & 63, ty = tid >> 6;
  __shared__ float f0s[64], f1s[64];
  const float gm = gamma[0];
  if (tid < 64){
    int gi = b * HW + i0 + tid;
    float m0 = mbuf[gi], m1 = mbuf[NB * HW + gi];
    float l0 = lbuf[gi], l1 = lbuf[NB * HW + gi];
    float M = fmaxf(m0, m1);
    float w0 = exp2f(m0 - M), w1 = exp2f(m1 - M);  // m in log2 units
    float rden = 1.f / (w0 * l0 + w1 * l1);
    f0s[tid] = w0 * rden;
    f1s[tid] = w1 * rden;
  }
  __syncthreads();
  #pragma unroll
  for (int u = 0; u < 16; u++){
    int cl = ty * 16 + u;
    long idx = ((long)b * NC + c0 + cl) * HW + i0 + tx;
    float o = f0s[tx] * bf2f(p0[idx]) + f1s[tx] * bf2f(p1[idx]);
    out[idx] = fmaf(gm, o, x[idx]);
  }
}

extern "C" void kernel_launch(void* const* d_in, const int* in_sizes, int n_in,
                              void* d_out, int out_size, void* d_ws, size_t ws_size,
                              hipStream_t stream)
{
  const float* x  = (const float*)d_in[0];
  const float* Wq = (const float*)d_in[1];
  const float* bq = (const float*)d_in[2];
  const float* Wk = (const float*)d_in[3];
  const float* bk = (const float*)d_in[4];
  const float* Wv = (const float*)d_in[5];
  const float* bv = (const float*)d_in[6];
  const float* gamma = (const float*)d_in[7];
  float* out = (float*)d_out;

  char* ws = (char*)d_ws;
  const size_t MB = 1024 * 1024;
  ushort_t* xth = (ushort_t*)(ws);                 // 16 MB, reused as partial0
  ushort_t* xtl = (ushort_t*)(ws + 16 * MB);       // 16 MB, reused as partial1
  ushort_t* wh  = (ushort_t*)(ws + 32 * MB);       // 640 KB
  ushort_t* wl  = (ushort_t*)(ws + 32 * MB + 655360);  // 128 KB
  ushort_t* qhi = (ushort_t*)(ws + 33 * MB);       // 2 MB each
  ushort_t* qlo = (ushort_t*)(ws + 35 * MB);
  ushort_t* khi = (ushort_t*)(ws + 37 * MB);
  ushort_t* klo = (ushort_t*)(ws + 39 * MB);       // still written by gemm, unused by attn
  ushort_t* vv  = (ushort_t*)(ws + 41 * MB);       // 16 MB
  float*    mbuf = (float*)(ws + 57 * MB);         // 128 KB
  float*    lbuf = (float*)(ws + 57 * MB + 131072);// 128 KB
  ushort_t* part0 = xth;   // alias: xt dead after gemm
  ushort_t* part1 = xtl;

  wsplit_kernel<<<dim3(160), dim3(256), 0, stream>>>(Wq, Wk, Wv, wh, wl);
  split_kernel<<<dim3(64, 8, NB), dim3(256), 0, stream>>>(x, xth, xtl);

  const int GSMEM = 65536;
  hipFuncSetAttribute((const void*)gemm_kernel,
                      hipFuncAttributeMaxDynamicSharedMemorySize, GSMEM);
  gemm_kernel<<<dim3(32, 5, NB), dim3(256), GSMEM, stream>>>(
      xth, xtl, wh, wl, bq, bk, bv, qhi, qlo, khi, klo, vv);

  const int ASMEM = 147456;  // 16K K dbuf + 128K V dbuf
  hipFuncSetAttribute((const void*)attn_kernel,
                      hipFuncAttributeMaxDynamicSharedMemorySize, ASMEM);
  attn_kernel<<<dim3(256), dim3(512), ASMEM, stream>>>(
      qhi, qlo, khi, vv, part0, part1, mbuf, lbuf);

  comb_kernel<<<dim3(64, 8, NB), dim3(256), 0, stream>>>(
      part0, part1, mbuf, lbuf, x, gamma, out);
}

// Round 10
// 198.208 us; speedup vs baseline: 1.8293x; 1.0697x over previous
//
#include <hip/hip_runtime.h>
#include <hip/hip_bf16.h>
#include <math.h>

#define HW 4096
#define NC 512
#define NB 4

typedef float f32x4 __attribute__((ext_vector_type(4)));
typedef float f32x16 __attribute__((ext_vector_type(16)));
typedef short bf16x8 __attribute__((ext_vector_type(8)));
typedef unsigned int u32;
typedef u32 u32x4 __attribute__((ext_vector_type(4)));
typedef unsigned short ushort_t;

#define GLOAD_LDS(g, s) __builtin_amdgcn_global_load_lds((const __attribute__((address_space(1))) void*)(g), (__attribute__((address_space(3))) void*)(s), 16, 0, 0)

__device__ __forceinline__ unsigned short f2bf(float f){
  unsigned int u = __builtin_bit_cast(unsigned int, f);
  u += 0x7FFFu + ((u >> 16) & 1u);
  return (unsigned short)(u >> 16);
}
__device__ __forceinline__ float bf2f(unsigned short h){
  unsigned int u = ((unsigned int)h) << 16;
  return __builtin_bit_cast(float, u);
}

// ---------------- W -> bf16 hi (+lo for q/k rows 0..127) ----------------
__global__ __launch_bounds__(256) void wsplit_kernel(
    const float* __restrict__ Wq, const float* __restrict__ Wk,
    const float* __restrict__ Wv, ushort_t* __restrict__ wh, ushort_t* __restrict__ wl)
{
  long e = ((long)blockIdx.x * 256 + threadIdx.x) * 8;
  int r = (int)(e >> 9), c = (int)(e & 511);
  const float* src = (r < 64)  ? Wq + (long)r * 512 + c
                   : (r < 128) ? Wk + (long)(r - 64) * 512 + c
                               : Wv + (long)(r - 128) * 512 + c;
  f32x4 v0 = *reinterpret_cast<const f32x4*>(src);
  f32x4 v1 = *reinterpret_cast<const f32x4*>(src + 4);
  ushort_t h[8], l[8];
  #pragma unroll
  for (int j = 0; j < 4; j++){ h[j] = f2bf(v0[j]); l[j] = f2bf(v0[j] - bf2f(h[j])); }
  #pragma unroll
  for (int j = 0; j < 4; j++){ h[4+j] = f2bf(v1[j]); l[4+j] = f2bf(v1[j] - bf2f(h[4+j])); }
  *reinterpret_cast<bf16x8*>(wh + e) = *reinterpret_cast<bf16x8*>(h);
  if (r < 128) *reinterpret_cast<bf16x8*>(wl + e) = *reinterpret_cast<bf16x8*>(l);
}

// ---------------- x [b][c][px] fp32 -> xt hi/lo [b][px][c] bf16 ----------------
__global__ __launch_bounds__(256) void split_kernel(
    const float* __restrict__ x, ushort_t* __restrict__ xth, ushort_t* __restrict__ xtl)
{
  const int i0 = blockIdx.x * 64;
  const int c0 = blockIdx.y * 64;
  const int b  = blockIdx.z;
  const int tid = threadIdx.x;
  const int tx = tid & 63, ty = tid >> 6;
  __shared__ float ts[64][65];
  #pragma unroll
  for (int u = 0; u < 16; u++){
    int cl = ty * 16 + u;
    ts[cl][tx] = x[((long)b * NC + c0 + cl) * HW + i0 + tx];
  }
  __syncthreads();
  const int px = tid >> 2;
  const int cs = (tid & 3) * 16;
  ushort_t h[16], l[16];
  #pragma unroll
  for (int e = 0; e < 16; e++){
    float v = ts[cs + e][px];
    h[e] = f2bf(v);
    l[e] = f2bf(v - bf2f(h[e]));
  }
  long base = ((long)b * HW + i0 + px) * 512 + c0 + cs;
  *reinterpret_cast<bf16x8*>(xth + base)     = *reinterpret_cast<bf16x8*>(h);
  *reinterpret_cast<bf16x8*>(xth + base + 8) = *reinterpret_cast<bf16x8*>(h + 8);
  *reinterpret_cast<bf16x8*>(xtl + base)     = *reinterpret_cast<bf16x8*>(l);
  *reinterpret_cast<bf16x8*>(xtl + base + 8) = *reinterpret_cast<bf16x8*>(l + 8);
}

// ---------------- MFMA projection GEMM ----------------
__global__ __launch_bounds__(256) void gemm_kernel(
    const ushort_t* __restrict__ xth, const ushort_t* __restrict__ xtl,
    const ushort_t* __restrict__ wh, const ushort_t* __restrict__ wl,
    const float* __restrict__ bq, const float* __restrict__ bk, const float* __restrict__ bv,
    ushort_t* __restrict__ qhi, ushort_t* __restrict__ qlo,
    ushort_t* __restrict__ khi, ushort_t* __restrict__ klo,
    ushort_t* __restrict__ vv)
{
  extern __shared__ char lds[];
  const int it = blockIdx.x;
  const int rg = blockIdx.y;
  const int b  = blockIdx.z;
  const int i0 = it * 128;
  const int tid = threadIdx.x;
  const int w = tid >> 6;
  const int lane = tid & 63;
  const int g = lane >> 4, n = lane & 15;
  const int wy = w >> 1, wx = w & 1;

  f32x4 acc[4][4];
  #pragma unroll
  for (int a = 0; a < 4; a++)
    #pragma unroll
    for (int m = 0; m < 4; m++) acc[a][m] = (f32x4){0.f, 0.f, 0.f, 0.f};

  const long xrow = (long)b * HW + i0;

  auto stage = [&](int bsel, int c0s){
    char* dbase = lds + bsel * 32768 + (w << 10);
    #pragma unroll
    for (int u = 0; u < 4; u++){
      int idx = (u << 8) | tid;
      int px = idx >> 3;
      int chs = (idx & 7) ^ (px & 7);
      long go = (xrow + px) * 512 + c0s + chs * 8;
      GLOAD_LDS(xth + go, dbase + (u << 12));
      GLOAD_LDS(xtl + go, dbase + 16384 + (u << 12));
    }
  };

  stage(0, 0);
  asm volatile("s_waitcnt vmcnt(0)" ::: "memory");
  __syncthreads();

  int cur = 0;
  for (int t = 0; t < 8; t++){
    const int c0 = t << 6;
    bf16x8 wfh[4][2], wfl[4][2];
    #pragma unroll
    for (int a = 0; a < 4; a++){
      long R = (long)(rg * 128 + wx * 64 + a * 16 + n) * 512 + c0 + g * 8;
      wfh[a][0] = *reinterpret_cast<const bf16x8*>(wh + R);
      wfh[a][1] = *reinterpret_cast<const bf16x8*>(wh + R + 32);
    }
    if (rg == 0){
      #pragma unroll
      for (int a = 0; a < 4; a++){
        long R = (long)(wx * 64 + a * 16 + n) * 512 + c0 + g * 8;
        wfl[a][0] = *reinterpret_cast<const bf16x8*>(wl + R);
        wfl[a][1] = *reinterpret_cast<const bf16x8*>(wl + R + 32);
      }
    }
    if (t < 7) stage(cur ^ 1, (t + 1) << 6);
    bf16x8 xh[4][2], xl[4][2];
    const char* buf = lds + cur * 32768;
    #pragma unroll
    for (int m = 0; m < 4; m++){
      int px = wy * 64 + m * 16 + n;
      const char* row = buf + px * 128;
      #pragma unroll
      for (int ks = 0; ks < 2; ks++){
        int off = (((ks << 2) | g) ^ (px & 7)) << 4;
        xh[m][ks] = *reinterpret_cast<const bf16x8*>(row + off);
        xl[m][ks] = *reinterpret_cast<const bf16x8*>(row + 16384 + off);
      }
    }
    __builtin_amdgcn_s_setprio(1);
    if (rg == 0){
      #pragma unroll
      for (int a = 0; a < 4; a++)
        #pragma unroll
        for (int m = 0; m < 4; m++)
          #pragma unroll
          for (int ks = 0; ks < 2; ks++){
            acc[a][m] = __builtin_amdgcn_mfma_f32_16x16x32_bf16(xh[m][ks], wfh[a][ks], acc[a][m], 0, 0, 0);
            acc[a][m] = __builtin_amdgcn_mfma_f32_16x16x32_bf16(xl[m][ks], wfh[a][ks], acc[a][m], 0, 0, 0);
            acc[a][m] = __builtin_amdgcn_mfma_f32_16x16x32_bf16(xh[m][ks], wfl[a][ks], acc[a][m], 0, 0, 0);
          }
    } else {
      #pragma unroll
      for (int a = 0; a < 4; a++)
        #pragma unroll
        for (int m = 0; m < 4; m++)
          #pragma unroll
          for (int ks = 0; ks < 2; ks++){
            acc[a][m] = __builtin_amdgcn_mfma_f32_16x16x32_bf16(wfh[a][ks], xh[m][ks], acc[a][m], 0, 0, 0);
            acc[a][m] = __builtin_amdgcn_mfma_f32_16x16x32_bf16(wfh[a][ks], xl[m][ks], acc[a][m], 0, 0, 0);
          }
    }
    __builtin_amdgcn_s_setprio(0);
    asm volatile("s_waitcnt vmcnt(0)" ::: "memory");
    __syncthreads();
    cur ^= 1;
  }

  if (rg == 0){
    ushort_t* hs = wx ? khi : qhi;
    ushort_t* ls = wx ? klo : qlo;
    const float* bias = wx ? bk : bq;
    const float qscale = wx ? 1.0f : 1.44269504088896f;  // q in log2 domain
    #pragma unroll
    for (int a = 0; a < 4; a++){
      float bb = bias[a * 16 + n];
      #pragma unroll
      for (int m = 0; m < 4; m++){
        #pragma unroll
        for (int r4 = 0; r4 < 4; r4++){
          int px = wy * 64 + m * 16 + g * 4 + r4;
          float v = (acc[a][m][r4] + bb) * qscale;
          ushort_t h = f2bf(v);
          ushort_t l = f2bf(v - bf2f(h));
          long ad = (xrow + px) * 64 + a * 16 + n;
          hs[ad] = h;
          ls[ad] = l;
        }
      }
    }
  } else {
    #pragma unroll
    for (int a = 0; a < 4; a++){
      #pragma unroll
      for (int r4 = 0; r4 < 4; r4++){
        int C = (rg - 1) * 128 + wx * 64 + a * 16 + g * 4 + r4;
        float bb = bv[C];
        #pragma unroll
        for (int m = 0; m < 4; m++){
          int px = wy * 64 + m * 16 + n;
          vv[((long)b * NC + C) * HW + i0 + px] = f2bf(acc[a][m][r4] + bb);
        }
      }
    }
  }
}

// ---------------- flash attention: producer/consumer softmax dedup ----------------
// 1D grid 256; decode: xcd = wgid&7 -> (jh = xcd>>2, b = xcd&3), qt = wgid>>3.
// Block 512 thr (8 waves): w<4 -> PRODUCER (rg=w, ch=0): QK + softmax + pack,
// publish pa/flag/sc via LDS. w>=4 -> CONSUMER (rg=w-4, ch=1): stage V[t+1] in
// phase 1, then stage K[t+1] + read pa + join PV in phase 2. Halves softmax VALU,
// QK MFMA, and K LDS reads (no ch-duplication).
// LDS 153K: [0,8K) K single | [8K,136K) V dbuf | [136K,152K) P (4K/rg) | [152K,+1K) flags/sc
__global__ __launch_bounds__(512, 1) void attn_kernel(
    const ushort_t* __restrict__ qhi, const ushort_t* __restrict__ qlo,
    const ushort_t* __restrict__ khi,
    const ushort_t* __restrict__ vv,
    ushort_t* __restrict__ p0, ushort_t* __restrict__ p1,
    float* __restrict__ mbuf, float* __restrict__ lbuf)
{
  extern __shared__ char smem[];
  const int VB = 8192, PB = 139264, FB = 155648;
  const int wgid = blockIdx.x;
  const int xcd = wgid & 7;
  const int jh = xcd >> 2;
  const int b  = xcd & 3;
  const int qt = wgid >> 3;
  const int tid = threadIdx.x;
  const int w = tid >> 6;
  const int lane = tid & 63;
  const int q32 = lane & 31;
  const int hh = lane >> 5;
  const bool producer = (w < 4);
  const int rg = producer ? w : (w - 4);
  const int ch = producer ? 0 : 1;
  const int i0w = qt * 128 + rg * 32;
  const int c0w = ch * 256;
  const int jbase = jh * 2048;
  const int ct256 = ((w & 3) << 6) | lane;   // consumer staging index

  // Q fragments (B-operand): col q = lane&31, k(d) = chain*16 + hh*8 + e
  bf16x8 aqh[4], aql[4];
  #pragma unroll
  for (int c = 0; c < 4; c++){
    long qb = ((long)b * HW + i0w + q32) * 64 + c * 16 + hh * 8;
    aqh[c] = *reinterpret_cast<const bf16x8*>(qhi + qb);
    aql[c] = *reinterpret_cast<const bf16x8*>(qlo + qb);
  }

  f32x16 acc[8];
  #pragma unroll
  for (int ct = 0; ct < 8; ct++)
    #pragma unroll
    for (int r = 0; r < 16; r++) acc[ct][r] = 0.f;
  float mrow = -1e30f, lrow = 0.f;

  // ---- prologue: all 512 threads stage K[0] (single buf) + V[0] (buf0)
  {
    int kj = tid >> 3;
    int kd = (tid & 7) ^ (kj & 7);
    GLOAD_LDS(khi + ((long)b * HW + jbase + kj) * 64 + kd * 8, smem + (w << 10));
    #pragma unroll
    for (int r = 0; r < 8; r++){
      int ss = (r << 9) | tid;
      int c = ss >> 3;
      int jblk = (ss & 7) ^ (c & 7);
      GLOAD_LDS(vv + ((long)b * NC + c) * HW + jbase + jblk * 8,
                smem + VB + (r << 13) + (w << 10));
    }
  }
  asm volatile("s_waitcnt vmcnt(0)" ::: "memory");
  __syncthreads();

  int cur = 0;
  for (int t = 0; t < 32; t++){
    bf16x8 pa[4];
    // ================= phase 1 =================
    if (producer){
      // QK swapped: S[j, q] = kh·(qh + ql), log2 domain (K single buffer)
      f32x16 sv[2];
      __builtin_amdgcn_s_setprio(1);
      #pragma unroll
      for (int jt = 0; jt < 2; jt++){
        int jrow = jt * 32 + q32;
        const char* krow = smem + jrow * 128;
        int r7 = jrow & 7;
        f32x16 s;
        #pragma unroll
        for (int r = 0; r < 16; r++) s[r] = 0.f;
        #pragma unroll
        for (int c = 0; c < 4; c++){
          int off = (((c << 1) | hh) ^ r7) << 4;
          bf16x8 kh = *(const bf16x8*)(krow + off);
          s = __builtin_amdgcn_mfma_f32_32x32x16_bf16(kh, aqh[c], s, 0, 0, 0);
          s = __builtin_amdgcn_mfma_f32_32x32x16_bf16(kh, aql[c], s, 0, 0, 0);
        }
        sv[jt] = s;
      }
      __builtin_amdgcn_s_setprio(0);
      // softmax with defer-max (log2 units)
      f32x16 mx;
      #pragma unroll
      for (int r = 0; r < 16; r++) mx[r] = fmaxf(sv[0][r], sv[1][r]);
      float m8[8];
      #pragma unroll
      for (int r = 0; r < 8; r++) m8[r] = fmaxf(mx[r], mx[r + 8]);
      float m4a = fmaxf(m8[0], m8[4]), m4b = fmaxf(m8[1], m8[5]);
      float m4c = fmaxf(m8[2], m8[6]), m4d = fmaxf(m8[3], m8[7]);
      float tmx = fmaxf(fmaxf(m4a, m4b), fmaxf(m4c, m4d));
      tmx = fmaxf(tmx, __shfl_xor(tmx, 32));
      int upd = __any(tmx > mrow + 11.5f) ? 1 : 0;
      float sc = 1.f;
      if (upd){
        float mnew = fmaxf(mrow, tmx);
        sc = exp2f(mrow - mnew);
        lrow *= sc;
        #pragma unroll
        for (int ct = 0; ct < 8; ct++)
          #pragma unroll
          for (int r = 0; r < 16; r++) acc[ct][r] *= sc;
        mrow = mnew;
      }
      // P = exp2(S - m), row-sum, pack
      #pragma unroll
      for (int jt = 0; jt < 2; jt++)
        #pragma unroll
        for (int r = 0; r < 16; r++) sv[jt][r] = exp2f(sv[jt][r] - mrow);
      float rs = 0.f;
      #pragma unroll
      for (int r = 0; r < 16; r++) rs += sv[0][r] + sv[1][r];
      rs += __shfl_xor(rs, 32);
      lrow += rs;
      #pragma unroll
      for (int jt = 0; jt < 2; jt++){
        u32 pk[8];
        #pragma unroll
        for (int i = 0; i < 8; i++){
          float a = sv[jt][2 * i], bb = sv[jt][2 * i + 1];
          u32 d;
          asm("v_cvt_pk_bf16_f32 %0, %1, %2" : "=v"(d) : "v"(a), "v"(bb));
          pk[i] = d;
        }
        #pragma unroll
        for (int cc = 0; cc < 2; cc++){
          u32 a0 = pk[4 * cc + 0], b0 = pk[4 * cc + 2];
          u32 a1 = pk[4 * cc + 1], b1 = pk[4 * cc + 3];
          asm volatile("v_permlane32_swap_b32 %0, %1" : "+v"(a0), "+v"(b0));
          asm volatile("v_permlane32_swap_b32 %0, %1" : "+v"(a1), "+v"(b1));
          u32x4 wv;
          wv[0] = a0; wv[1] = a1; wv[2] = b0; wv[3] = b1;
          pa[jt * 2 + cc] = __builtin_bit_cast(bf16x8, wv);
        }
      }
      // publish pa (XOR'd 16B chunks, 2-way-free banks), flag, sc
      char* pb = smem + PB + rg * 4096 + lane * 64;
      #pragma unroll
      for (int i = 0; i < 4; i++)
        *reinterpret_cast<bf16x8*>(pb + ((i ^ (lane & 3)) << 4)) = pa[i];
      if (lane == 0) *(int*)(smem + FB + rg * 4) = upd;
      if (upd && hh == 0) *(float*)(smem + FB + 64 + rg * 128 + q32 * 4) = sc;
    } else {
      // consumer: stage V[t+1] -> vbuf^1 (16 loads; lands by end-of-iter vmcnt)
      if (t < 31){
        char* dbase = smem + VB + ((cur ^ 1) << 16) + ((w & 3) << 10);
        int j0 = jbase + (t + 1) * 64;
        #pragma unroll
        for (int r = 0; r < 16; r++){
          int ss = (r << 8) | ct256;
          int c = ss >> 3;
          int jblk = (ss & 7) ^ (c & 7);
          GLOAD_LDS(vv + ((long)b * NC + c) * HW + j0 + jblk * 8, dbase + (r << 12));
        }
      }
    }
    __syncthreads();   // bar1: pa/flag/sc published; V[t] settled reads done
    // ================= phase 2 =================
    if (!producer){
      // stage K[t+1] into the single K buffer (readers done at bar1)
      if (t < 31){
        int j0 = jbase + (t + 1) * 64;
        #pragma unroll
        for (int r = 0; r < 2; r++){
          int chunk = (r << 8) | ct256;
          int kj = chunk >> 3;
          int kd = (chunk & 7) ^ (kj & 7);
          GLOAD_LDS(khi + ((long)b * HW + j0 + kj) * 64 + kd * 8,
                    smem + (r << 12) + ((w & 3) << 10));
        }
      }
      // fetch pa + rescale decision from producer
      const char* pb = smem + PB + rg * 4096 + lane * 64;
      #pragma unroll
      for (int i = 0; i < 4; i++)
        pa[i] = *reinterpret_cast<const bf16x8*>(pb + ((i ^ (lane & 3)) << 4));
      int updf = *(const int*)(smem + FB + rg * 4);
      if (updf){
        float sc = *(const float*)(smem + FB + 64 + rg * 128 + q32 * 4);
        #pragma unroll
        for (int ct = 0; ct < 8; ct++)
          #pragma unroll
          for (int r = 0; r < 16; r++) acc[ct][r] *= sc;
      }
    }
    // PV on V[cur] (both producer and consumer, disjoint c-halves)
    {
      const char* vb = smem + VB + (cur << 16);
      __builtin_amdgcn_s_setprio(1);
      #pragma unroll
      for (int ct = 0; ct < 8; ct++){
        int row = c0w + ct * 32 + q32;
        const char* vrow = vb + row * 128;
        int r7 = row & 7;
        #pragma unroll
        for (int c = 0; c < 4; c++){
          int off = (((c << 1) | hh) ^ r7) << 4;
          bf16x8 vf = *(const bf16x8*)(vrow + off);
          acc[ct] = __builtin_amdgcn_mfma_f32_32x32x16_bf16(vf, pa[c], acc[ct], 0, 0, 0);
        }
      }
      __builtin_amdgcn_s_setprio(0);
    }
    // bar2: drain own staging (V issued ph1, K issued ph2), publish buffers
    asm volatile("s_waitcnt vmcnt(0)" ::: "memory");
    __syncthreads();
    cur ^= 1;
  }

  // epilogue: unnormalized partial bf16, [b][c][i] layout (coalesced in i)
  ushort_t* pd = jh ? p1 : p0;
  const int i = i0w + q32;
  #pragma unroll
  for (int ct = 0; ct < 8; ct++){
    #pragma unroll
    for (int r = 0; r < 16; r++){
      int c = c0w + ct * 32 + (r & 3) + 8 * (r >> 2) + 4 * hh;
      pd[((long)b * NC + c) * HW + i] = f2bf(acc[ct][r]);
    }
  }
  if (producer && lane < 32){
    int gi = b * HW + i0w + lane;
    mbuf[jh * (NB * HW) + gi] = mrow;
    lbuf[jh * (NB * HW) + gi] = lrow;
  }
}

// ---------------- combine halves + epilogue: out = gamma * O + x ----------------
__global__ __launch_bounds__(256) void comb_kernel(
    const ushort_t* __restrict__ p0, const ushort_t* __restrict__ p1,
    const float* __restrict__ mbuf, const float* __restrict__ lbuf,
    const float* __restrict__ x, const float* __restrict__ gamma,
    float* __restrict__ out)
{
  const int it = blockIdx.x;
  const int ct = blockIdx.y;
  const int b  = blockIdx.z;
  const int i0 = it * 64, c0 = ct * 64;
  const int tid = threadIdx.x;
  const int tx = tid & 63, ty = tid >> 6;
  __shared__ float f0s[64], f1s[64];
  const float gm = gamma[0];
  if (tid < 64){
    int gi = b * HW + i0 + tid;
    float m0 = mbuf[gi], m1 = mbuf[NB * HW + gi];
    float l0 = lbuf[gi], l1 = lbuf[NB * HW + gi];
    float M = fmaxf(m0, m1);
    float w0 = exp2f(m0 - M), w1 = exp2f(m1 - M);  // m in log2 units
    float rden = 1.f / (w0 * l0 + w1 * l1);
    f0s[tid] = w0 * rden;
    f1s[tid] = w1 * rden;
  }
  __syncthreads();
  #pragma unroll
  for (int u = 0; u < 16; u++){
    int cl = ty * 16 + u;
    long idx = ((long)b * NC + c0 + cl) * HW + i0 + tx;
    float o = f0s[tx] * bf2f(p0[idx]) + f1s[tx] * bf2f(p1[idx]);
    out[idx] = fmaf(gm, o, x[idx]);
  }
}

extern "C" void kernel_launch(void* const* d_in, const int* in_sizes, int n_in,
                              void* d_out, int out_size, void* d_ws, size_t ws_size,
                              hipStream_t stream)
{
  const float* x  = (const float*)d_in[0];
  const float* Wq = (const float*)d_in[1];
  const float* bq = (const float*)d_in[2];
  const float* Wk = (const float*)d_in[3];
  const float* bk = (const float*)d_in[4];
  const float* Wv = (const float*)d_in[5];
  const float* bv = (const float*)d_in[6];
  const float* gamma = (const float*)d_in[7];
  float* out = (float*)d_out;

  char* ws = (char*)d_ws;
  const size_t MB = 1024 * 1024;
  ushort_t* xth = (ushort_t*)(ws);                 // 16 MB, reused as partial0
  ushort_t* xtl = (ushort_t*)(ws + 16 * MB);       // 16 MB, reused as partial1
  ushort_t* wh  = (ushort_t*)(ws + 32 * MB);       // 640 KB
  ushort_t* wl  = (ushort_t*)(ws + 32 * MB + 655360);  // 128 KB
  ushort_t* qhi = (ushort_t*)(ws + 33 * MB);       // 2 MB each
  ushort_t* qlo = (ushort_t*)(ws + 35 * MB);
  ushort_t* khi = (ushort_t*)(ws + 37 * MB);
  ushort_t* klo = (ushort_t*)(ws + 39 * MB);       // written by gemm, unused by attn
  ushort_t* vv  = (ushort_t*)(ws + 41 * MB);       // 16 MB
  float*    mbuf = (float*)(ws + 57 * MB);         // 128 KB
  float*    lbuf = (float*)(ws + 57 * MB + 131072);// 128 KB
  ushort_t* part0 = xth;   // alias: xt dead after gemm
  ushort_t* part1 = xtl;

  wsplit_kernel<<<dim3(160), dim3(256), 0, stream>>>(Wq, Wk, Wv, wh, wl);
  split_kernel<<<dim3(64, 8, NB), dim3(256), 0, stream>>>(x, xth, xtl);

  const int GSMEM = 65536;
  hipFuncSetAttribute((const void*)gemm_kernel,
                      hipFuncAttributeMaxDynamicSharedMemorySize, GSMEM);
  gemm_kernel<<<dim3(32, 5, NB), dim3(256), GSMEM, stream>>>(
      xth, xtl, wh, wl, bq, bk, bv, qhi, qlo, khi, klo, vv);

  const int ASMEM = 156672;  // 8K K + 128K V dbuf + 16K P + 1K flags
  hipFuncSetAttribute((const void*)attn_kernel,
                      hipFuncAttributeMaxDynamicSharedMemorySize, ASMEM);
  attn_kernel<<<dim3(256), dim3(512), ASMEM, stream>>>(
      qhi, qlo, khi, vv, part0, part1, mbuf, lbuf);

  comb_kernel<<<dim3(64, 8, NB), dim3(256), 0, stream>>>(
      part0, part1, mbuf, lbuf, x, gamma, out);
}